// Round 8
// baseline (337.603 us; speedup 1.0000x reference)
//
#include <hip/hip_runtime.h>
#include <cstdint>

#define NEG_SLOPE 0.2f
#define MAXDEG 64

// ---------------- bucketed CSR build: 1 atomic per edge, 4 edges/thread ----------------

__global__ __launch_bounds__(256) void k_init(int* __restrict__ cursor, int N) {
    int i = blockIdx.x * 256 + threadIdx.x;
    if (i < N) cursor[i] = i * MAXDEG;
}

__global__ __launch_bounds__(256) void k_fillb(const int* __restrict__ ei, const float* __restrict__ ew,
                                               int* __restrict__ cursor, int2* __restrict__ bucket, int E) {
    int i0 = (blockIdx.x * 256 + threadIdx.x) * 4;
    if (i0 >= E) return;
    if (i0 + 3 < E) {
        int4 s4 = *(const int4*)&ei[i0];
        int4 d4 = *(const int4*)&ei[E + i0];
        float4 w4 = *(const float4*)&ew[i0];
        int p0 = atomicAdd(&cursor[d4.x], 1);
        int p1 = atomicAdd(&cursor[d4.y], 1);
        int p2 = atomicAdd(&cursor[d4.z], 1);
        int p3 = atomicAdd(&cursor[d4.w], 1);
        bucket[p0] = make_int2(s4.x, __float_as_int(w4.x));
        bucket[p1] = make_int2(s4.y, __float_as_int(w4.y));
        bucket[p2] = make_int2(s4.z, __float_as_int(w4.z));
        bucket[p3] = make_int2(s4.w, __float_as_int(w4.w));
    } else {
        for (int i = i0; i < E; ++i) {
            int pos = atomicAdd(&cursor[ei[E + i]], 1);
            bucket[pos] = make_int2(ei[i], __float_as_int(ew[i]));
        }
    }
}

// ---------------- Fused GEMM: Ol = H@Wl, Or = H@Wr (f32), 64 rows/block ----------------
// Register-staged pipeline: next chunk's global loads issue before compute,
// commit to LDS after the post-compute barrier (latency hidden under 32-k compute).
__global__ __launch_bounds__(256) void k_gemm2(const float* __restrict__ H, const float* __restrict__ Wl,
                                               const float* __restrict__ Wr, float* __restrict__ Ol,
                                               float* __restrict__ Or, int N) {
    __shared__ __align__(16) float Wsl[32][128];
    __shared__ __align__(16) float Wsr[32][128];
    __shared__ __align__(16) float Hs[32][72];   // k-major, 64 rows + pad
    int t = threadIdx.x;
    int tx = t & 31, ty = t >> 5;
    int r0 = blockIdx.x * 64;
    float accl[8][4] = {}, accr[8][4] = {};

    float4 wlR[4], wrR[4], hR[2];
    auto issue = [&](int kc) {
#pragma unroll
        for (int i = 0; i < 4; ++i) {
            int idx = (i * 256 + t) * 4;
            int kk = idx >> 7, cc = idx & 127;
            wlR[i] = *(const float4*)&Wl[(size_t)(kc + kk) * 128 + cc];
            wrR[i] = *(const float4*)&Wr[(size_t)(kc + kk) * 128 + cc];
        }
#pragma unroll
        for (int i = 0; i < 2; ++i) {
            int f = i * 256 + t;
            int rr = f >> 3;
            int k4 = (f & 7) * 4;
            int r = r0 + rr;
            hR[i] = (r < N) ? *(const float4*)&H[(size_t)r * 128 + kc + k4]
                            : make_float4(0.f, 0.f, 0.f, 0.f);
        }
    };
    auto commit = [&]() {
#pragma unroll
        for (int i = 0; i < 4; ++i) {
            int idx = (i * 256 + t) * 4;
            int kk = idx >> 7, cc = idx & 127;
            *(float4*)&Wsl[kk][cc] = wlR[i];
            *(float4*)&Wsr[kk][cc] = wrR[i];
        }
#pragma unroll
        for (int i = 0; i < 2; ++i) {
            int f = i * 256 + t;
            int rr = f >> 3;
            int k4 = (f & 7) * 4;
            Hs[k4 + 0][rr] = hR[i].x;
            Hs[k4 + 1][rr] = hR[i].y;
            Hs[k4 + 2][rr] = hR[i].z;
            Hs[k4 + 3][rr] = hR[i].w;
        }
    };

    issue(0);
    commit();
    __syncthreads();
    for (int c = 0; c < 4; ++c) {
        if (c < 3) issue((c + 1) * 32);          // overlap with compute below
#pragma unroll 4
        for (int k = 0; k < 32; ++k) {
            float4 wl4 = *(float4*)&Wsl[k][tx * 4];
            float4 wr4 = *(float4*)&Wsr[k][tx * 4];
            float4 ha  = *(float4*)&Hs[k][ty * 8];
            float4 hb  = *(float4*)&Hs[k][ty * 8 + 4];
            float hv[8] = {ha.x, ha.y, ha.z, ha.w, hb.x, hb.y, hb.z, hb.w};
            float wlv[4] = {wl4.x, wl4.y, wl4.z, wl4.w};
            float wrv[4] = {wr4.x, wr4.y, wr4.z, wr4.w};
#pragma unroll
            for (int i = 0; i < 8; ++i)
#pragma unroll
                for (int j = 0; j < 4; ++j) {
                    accl[i][j] += hv[i] * wlv[j];
                    accr[i][j] += hv[i] * wrv[j];
                }
        }
        if (c < 3) {
            __syncthreads();                     // all reads of LDS done
            commit();                            // write staged regs (waits vmcnt here)
            __syncthreads();                     // visible to all
        }
    }
#pragma unroll
    for (int i = 0; i < 8; ++i) {
        int r = r0 + ty * 8 + i;
        if (r < N) {
            *(float4*)&Ol[(size_t)r * 128 + tx * 4] = make_float4(accl[i][0], accl[i][1], accl[i][2], accl[i][3]);
            *(float4*)&Or[(size_t)r * 128 + tx * 4] = make_float4(accr[i][0], accr[i][1], accr[i][2], accr[i][3]);
        }
    }
}

// ---------------- Node kernel: one wave per node, 8 edges in flight (2x4 paired) ----------------
__global__ __launch_bounds__(256) void k_node(const float* __restrict__ xl, const float* __restrict__ xr,
                                              const int* __restrict__ cursor, const int2* __restrict__ bucket,
                                              const float* __restrict__ We, const float* __restrict__ att,
                                              const float* __restrict__ bias, float* __restrict__ out, int N) {
    int wid = threadIdx.x >> 6;
    int lane = threadIdx.x & 63;
    int n = blockIdx.x * 4 + wid;
    if (n >= N) return;
    int sub = lane & 15, e4 = lane >> 4;
    int d0 = sub * 8;
    float4 weA = *(const float4*)(We + d0),  weB = *(const float4*)(We + d0 + 4);
    float4 atA = *(const float4*)(att + d0), atB = *(const float4*)(att + d0 + 4);
    const float* xrp = xr + (size_t)n * 128 + d0;
    float4 xrA = *(const float4*)xrp, xrB = *(const float4*)(xrp + 4);
    int beg = n * MAXDEG;
    int end = cursor[n];
    int deg = end - beg;
    int iters = (deg + 7) >> 3;                  // 8 edge slots per iteration
    float den = 0.f, wacc = 0.f;
    float a0 = 0.f, a1 = 0.f, a2 = 0.f, a3 = 0.f, a4 = 0.f, a5 = 0.f, a6 = 0.f, a7 = 0.f;
    for (int it = 0; it < iters; ++it) {
        int idx0 = beg + it * 8 + e4;
        int idx1 = idx0 + 4;
        bool v0 = idx0 < end, v1 = idx1 < end;
        int2 rec0 = bucket[idx0];
        int2 rec1 = bucket[idx1];
        int s0 = v0 ? rec0.x : n;
        int s1 = v1 ? rec1.x : n;
        float w0 = v0 ? __int_as_float(rec0.y) : 0.f;
        float w1 = v1 ? __int_as_float(rec1.y) : 0.f;
        const float* xp0 = xl + (size_t)s0 * 128 + d0;
        const float* xp1 = xl + (size_t)s1 * 128 + d0;
        float4 x0A = *(const float4*)xp0;
        float4 x0B = *(const float4*)(xp0 + 4);
        float4 x1A = *(const float4*)xp1;
        float4 x1B = *(const float4*)(xp1 + 4);
        float t0 = fmaf(w0, weA.x, x0A.x + xrA.x);
        float t1 = fmaf(w0, weA.y, x0A.y + xrA.y);
        float t2 = fmaf(w0, weA.z, x0A.z + xrA.z);
        float t3 = fmaf(w0, weA.w, x0A.w + xrA.w);
        float t4 = fmaf(w0, weB.x, x0B.x + xrB.x);
        float t5 = fmaf(w0, weB.y, x0B.y + xrB.y);
        float t6 = fmaf(w0, weB.z, x0B.z + xrB.z);
        float t7 = fmaf(w0, weB.w, x0B.w + xrB.w);
        t0 = fmaxf(t0, NEG_SLOPE * t0); t1 = fmaxf(t1, NEG_SLOPE * t1);
        t2 = fmaxf(t2, NEG_SLOPE * t2); t3 = fmaxf(t3, NEG_SLOPE * t3);
        t4 = fmaxf(t4, NEG_SLOPE * t4); t5 = fmaxf(t5, NEG_SLOPE * t5);
        t6 = fmaxf(t6, NEG_SLOPE * t6); t7 = fmaxf(t7, NEG_SLOPE * t7);
        float p0 = t0 * atA.x + t1 * atA.y + t2 * atA.z + t3 * atA.w
                 + t4 * atB.x + t5 * atB.y + t6 * atB.z + t7 * atB.w;
        float u0 = fmaf(w1, weA.x, x1A.x + xrA.x);
        float u1 = fmaf(w1, weA.y, x1A.y + xrA.y);
        float u2 = fmaf(w1, weA.z, x1A.z + xrA.z);
        float u3 = fmaf(w1, weA.w, x1A.w + xrA.w);
        float u4 = fmaf(w1, weB.x, x1B.x + xrB.x);
        float u5 = fmaf(w1, weB.y, x1B.y + xrB.y);
        float u6 = fmaf(w1, weB.z, x1B.z + xrB.z);
        float u7 = fmaf(w1, weB.w, x1B.w + xrB.w);
        u0 = fmaxf(u0, NEG_SLOPE * u0); u1 = fmaxf(u1, NEG_SLOPE * u1);
        u2 = fmaxf(u2, NEG_SLOPE * u2); u3 = fmaxf(u3, NEG_SLOPE * u3);
        u4 = fmaxf(u4, NEG_SLOPE * u4); u5 = fmaxf(u5, NEG_SLOPE * u5);
        u6 = fmaxf(u6, NEG_SLOPE * u6); u7 = fmaxf(u7, NEG_SLOPE * u7);
        float p1 = u0 * atA.x + u1 * atA.y + u2 * atA.z + u3 * atA.w
                 + u4 * atB.x + u5 * atB.y + u6 * atB.z + u7 * atB.w;
        p0 += __shfl_xor(p0, 1); p1 += __shfl_xor(p1, 1);
        p0 += __shfl_xor(p0, 2); p1 += __shfl_xor(p1, 2);
        p0 += __shfl_xor(p0, 4); p1 += __shfl_xor(p1, 4);
        float e0 = __expf(p0);
        float e1 = __expf(p1);
        e0 = v0 ? e0 : 0.f;
        e1 = v1 ? e1 : 0.f;
        den += e0 + e1;
        wacc += w0 + w1;
        a0 = fmaf(e0, x0A.x, fmaf(e1, x1A.x, a0));
        a1 = fmaf(e0, x0A.y, fmaf(e1, x1A.y, a1));
        a2 = fmaf(e0, x0A.z, fmaf(e1, x1A.z, a2));
        a3 = fmaf(e0, x0A.w, fmaf(e1, x1A.w, a3));
        a4 = fmaf(e0, x0B.x, fmaf(e1, x1B.x, a4));
        a5 = fmaf(e0, x0B.y, fmaf(e1, x1B.y, a5));
        a6 = fmaf(e0, x0B.z, fmaf(e1, x1B.z, a6));
        a7 = fmaf(e0, x0B.w, fmaf(e1, x1B.w, a7));
    }
#pragma unroll
    for (int off = 16; off <= 32; off <<= 1) {
        den += __shfl_xor(den, off);
        wacc += __shfl_xor(wacc, off);
        a0 += __shfl_xor(a0, off); a1 += __shfl_xor(a1, off);
        a2 += __shfl_xor(a2, off); a3 += __shfl_xor(a3, off);
        a4 += __shfl_xor(a4, off); a5 += __shfl_xor(a5, off);
        a6 += __shfl_xor(a6, off); a7 += __shfl_xor(a7, off);
    }
    // self-loop: weight = mean incoming edge weight, source feature = xl[n]
    {
        float lw = wacc / (float)max(deg, 1);
        const float* xp = xl + (size_t)n * 128 + d0;
        float4 xA = *(const float4*)xp;
        float4 xB = *(const float4*)(xp + 4);
        float t0 = fmaf(lw, weA.x, xA.x + xrA.x);
        float t1 = fmaf(lw, weA.y, xA.y + xrA.y);
        float t2 = fmaf(lw, weA.z, xA.z + xrA.z);
        float t3 = fmaf(lw, weA.w, xA.w + xrA.w);
        float t4 = fmaf(lw, weB.x, xB.x + xrB.x);
        float t5 = fmaf(lw, weB.y, xB.y + xrB.y);
        float t6 = fmaf(lw, weB.z, xB.z + xrB.z);
        float t7 = fmaf(lw, weB.w, xB.w + xrB.w);
        t0 = fmaxf(t0, NEG_SLOPE * t0); t1 = fmaxf(t1, NEG_SLOPE * t1);
        t2 = fmaxf(t2, NEG_SLOPE * t2); t3 = fmaxf(t3, NEG_SLOPE * t3);
        t4 = fmaxf(t4, NEG_SLOPE * t4); t5 = fmaxf(t5, NEG_SLOPE * t5);
        t6 = fmaxf(t6, NEG_SLOPE * t6); t7 = fmaxf(t7, NEG_SLOPE * t7);
        float p = t0 * atA.x + t1 * atA.y + t2 * atA.z + t3 * atA.w
                + t4 * atB.x + t5 * atB.y + t6 * atB.z + t7 * atB.w;
        p += __shfl_xor(p, 1);
        p += __shfl_xor(p, 2);
        p += __shfl_xor(p, 4);
        float e = __expf(p);
        den += e;
        a0 = fmaf(e, xA.x, a0); a1 = fmaf(e, xA.y, a1);
        a2 = fmaf(e, xA.z, a2); a3 = fmaf(e, xA.w, a3);
        a4 = fmaf(e, xB.x, a4); a5 = fmaf(e, xB.y, a5);
        a6 = fmaf(e, xB.z, a6); a7 = fmaf(e, xB.w, a7);
    }
    float inv = 1.f / den;
    float4 biA = *(const float4*)(bias + d0), biB = *(const float4*)(bias + d0 + 4);
    float o0 = a0 * inv + biA.x, o1 = a1 * inv + biA.y;
    float o2 = a2 * inv + biA.z, o3 = a3 * inv + biA.w;
    float o4 = a4 * inv + biB.x, o5 = a5 * inv + biB.y;
    float o6 = a6 * inv + biB.z, o7 = a7 * inv + biB.w;
    o0 = o0 > 0.f ? o0 : expm1f(o0); o1 = o1 > 0.f ? o1 : expm1f(o1);
    o2 = o2 > 0.f ? o2 : expm1f(o2); o3 = o3 > 0.f ? o3 : expm1f(o3);
    o4 = o4 > 0.f ? o4 : expm1f(o4); o5 = o5 > 0.f ? o5 : expm1f(o5);
    o6 = o6 > 0.f ? o6 : expm1f(o6); o7 = o7 > 0.f ? o7 : expm1f(o7);
    if (e4 == 0) {
        float* op = out + (size_t)n * 128 + d0;
        *(float4*)op       = make_float4(o0, o1, o2, o3);
        *(float4*)(op + 4) = make_float4(o4, o5, o6, o7);
    }
}

// ---------------- launch ----------------

extern "C" void kernel_launch(void* const* d_in, const int* in_sizes, int n_in,
                              void* d_out, int out_size, void* d_ws, size_t ws_size,
                              hipStream_t stream) {
    const int*   ei   = (const int*)d_in[0];
    const float* ew   = (const float*)d_in[1];
    const float* emb  = (const float*)d_in[2];
    const float* Wl   = (const float*)d_in[3];
    const float* Wr   = (const float*)d_in[4];
    const float* We   = (const float*)d_in[5];
    const float* att  = (const float*)d_in[6];
    const float* bias = (const float*)d_in[7];
    int E = in_sizes[1];
    int N = in_sizes[2] / 128;

    char* p = (char*)d_ws;
    auto alloc = [&](size_t bytes) { char* r = p; p += (bytes + 255) & ~(size_t)255; return r; };
    float* xl     = (float*)alloc((size_t)N * 128 * 4);
    float* xr     = (float*)alloc((size_t)N * 128 * 4);
    int2*  bucket = (int2*)alloc(((size_t)N * MAXDEG + 64) * 8);
    int*   cursor = (int*)alloc((size_t)N * 4);
    if ((size_t)(p - (char*)d_ws) > ws_size) return;   // workspace too small -> visible failure

    int ib = (N + 255) / 256;
    int fb = (E / 4 + 255) / 256;
    k_init<<<ib, 256, 0, stream>>>(cursor, N);
    k_fillb<<<fb, 256, 0, stream>>>(ei, ew, cursor, bucket, E);

    int gb = (N + 63) / 64;
    int nb = (N + 3) / 4;
    const float* h = emb;
    for (int l = 0; l < 2; ++l) {
        float* outl = (float*)d_out;               // layer0 result lives in d_out, re-read by layer1 gemm
        k_gemm2<<<gb, 256, 0, stream>>>(h, Wl + (size_t)l * 16384, Wr + (size_t)l * 16384, xl, xr, N);
        k_node<<<nb, 256, 0, stream>>>(xl, xr, cursor, bucket,
                                       We + (size_t)l * 128, att + (size_t)l * 128,
                                       bias + (size_t)l * 128, outl, N);
        h = outl;
    }
}

// Round 9
// 298.156 us; speedup vs baseline: 1.1323x; 1.1323x over previous
//
#include <hip/hip_runtime.h>
#include <cstdint>

#define NEG_SLOPE 0.2f
#define MAXDEG 64

// ---------------- bucketed CSR build: 1 atomic per edge, 4 edges/thread ----------------

__global__ __launch_bounds__(256) void k_init(int* __restrict__ cursor, int N) {
    int i = blockIdx.x * 256 + threadIdx.x;
    if (i < N) cursor[i] = i * MAXDEG;
}

__global__ __launch_bounds__(256) void k_fillb(const int* __restrict__ ei, const float* __restrict__ ew,
                                               int* __restrict__ cursor, int2* __restrict__ bucket, int E) {
    int i0 = (blockIdx.x * 256 + threadIdx.x) * 4;
    if (i0 >= E) return;
    if (i0 + 3 < E) {
        int4 s4 = *(const int4*)&ei[i0];
        int4 d4 = *(const int4*)&ei[E + i0];
        float4 w4 = *(const float4*)&ew[i0];
        int p0 = atomicAdd(&cursor[d4.x], 1);
        int p1 = atomicAdd(&cursor[d4.y], 1);
        int p2 = atomicAdd(&cursor[d4.z], 1);
        int p3 = atomicAdd(&cursor[d4.w], 1);
        bucket[p0] = make_int2(s4.x, __float_as_int(w4.x));
        bucket[p1] = make_int2(s4.y, __float_as_int(w4.y));
        bucket[p2] = make_int2(s4.z, __float_as_int(w4.z));
        bucket[p3] = make_int2(s4.w, __float_as_int(w4.w));
    } else {
        for (int i = i0; i < E; ++i) {
            int pos = atomicAdd(&cursor[ei[E + i]], 1);
            bucket[pos] = make_int2(ei[i], __float_as_int(ew[i]));
        }
    }
}

// ---------------- GEMM: O = H@W (f32), 64 rows/block; blockIdx.y picks (Wl,Ol)/(Wr,Or) ----------------
// Half-LDS variant: one 16KB W tile + 9KB H tile = ~26KB -> 6 blocks/CU (75% occ).
__global__ __launch_bounds__(256) void k_gemm(const float* __restrict__ H, const float* __restrict__ Wl,
                                              const float* __restrict__ Wr, float* __restrict__ Ol,
                                              float* __restrict__ Or, int N) {
    __shared__ __align__(16) float Ws[32][128];
    __shared__ __align__(16) float Hs[32][72];   // k-major, 64 rows + pad
    const float* W = blockIdx.y ? Wr : Wl;
    float*       O = blockIdx.y ? Or : Ol;
    int t = threadIdx.x;
    int tx = t & 31, ty = t >> 5;
    int r0 = blockIdx.x * 64;
    float acc[8][4] = {};
    for (int kc = 0; kc < 128; kc += 32) {
#pragma unroll
        for (int i = 0; i < 4; ++i) {
            int idx = (i * 256 + t) * 4;
            int kk = idx >> 7, cc = idx & 127;
            *(float4*)&Ws[kk][cc] = *(const float4*)&W[(size_t)(kc + kk) * 128 + cc];
        }
#pragma unroll
        for (int i = 0; i < 2; ++i) {
            int f = i * 256 + t;
            int rr = f >> 3;
            int k4 = (f & 7) * 4;
            int r = r0 + rr;
            float4 v = make_float4(0.f, 0.f, 0.f, 0.f);
            if (r < N) v = *(const float4*)&H[(size_t)r * 128 + kc + k4];
            Hs[k4 + 0][rr] = v.x;
            Hs[k4 + 1][rr] = v.y;
            Hs[k4 + 2][rr] = v.z;
            Hs[k4 + 3][rr] = v.w;
        }
        __syncthreads();
#pragma unroll 8
        for (int k = 0; k < 32; ++k) {
            float4 wv4 = *(float4*)&Ws[k][tx * 4];
            float4 ha  = *(float4*)&Hs[k][ty * 8];
            float4 hb  = *(float4*)&Hs[k][ty * 8 + 4];
            float hv[8] = {ha.x, ha.y, ha.z, ha.w, hb.x, hb.y, hb.z, hb.w};
            float wvv[4] = {wv4.x, wv4.y, wv4.z, wv4.w};
#pragma unroll
            for (int i = 0; i < 8; ++i)
#pragma unroll
                for (int j = 0; j < 4; ++j)
                    acc[i][j] += hv[i] * wvv[j];
        }
        __syncthreads();
    }
#pragma unroll
    for (int i = 0; i < 8; ++i) {
        int r = r0 + ty * 8 + i;
        if (r < N)
            *(float4*)&O[(size_t)r * 128 + tx * 4] = make_float4(acc[i][0], acc[i][1], acc[i][2], acc[i][3]);
    }
}

// ---------------- Node kernel: one wave per node, 8 edges in flight (2x4 paired) ----------------
__global__ __launch_bounds__(256) void k_node(const float* __restrict__ xl, const float* __restrict__ xr,
                                              const int* __restrict__ cursor, const int2* __restrict__ bucket,
                                              const float* __restrict__ We, const float* __restrict__ att,
                                              const float* __restrict__ bias, float* __restrict__ out, int N) {
    int wid = threadIdx.x >> 6;
    int lane = threadIdx.x & 63;
    int n = blockIdx.x * 4 + wid;
    if (n >= N) return;
    int sub = lane & 15, e4 = lane >> 4;
    int d0 = sub * 8;
    float4 weA = *(const float4*)(We + d0),  weB = *(const float4*)(We + d0 + 4);
    float4 atA = *(const float4*)(att + d0), atB = *(const float4*)(att + d0 + 4);
    const float* xrp = xr + (size_t)n * 128 + d0;
    float4 xrA = *(const float4*)xrp, xrB = *(const float4*)(xrp + 4);
    int beg = n * MAXDEG;
    int end = cursor[n];
    int deg = end - beg;
    int iters = (deg + 7) >> 3;                  // 8 edge slots per iteration
    float den = 0.f, wacc = 0.f;
    float a0 = 0.f, a1 = 0.f, a2 = 0.f, a3 = 0.f, a4 = 0.f, a5 = 0.f, a6 = 0.f, a7 = 0.f;
    for (int it = 0; it < iters; ++it) {
        int idx0 = beg + it * 8 + e4;
        int idx1 = idx0 + 4;
        bool v0 = idx0 < end, v1 = idx1 < end;
        int2 rec0 = bucket[idx0];
        int2 rec1 = bucket[idx1];
        int s0 = v0 ? rec0.x : n;
        int s1 = v1 ? rec1.x : n;
        float w0 = v0 ? __int_as_float(rec0.y) : 0.f;
        float w1 = v1 ? __int_as_float(rec1.y) : 0.f;
        const float* xp0 = xl + (size_t)s0 * 128 + d0;
        const float* xp1 = xl + (size_t)s1 * 128 + d0;
        float4 x0A = *(const float4*)xp0;
        float4 x0B = *(const float4*)(xp0 + 4);
        float4 x1A = *(const float4*)xp1;
        float4 x1B = *(const float4*)(xp1 + 4);
        float t0 = fmaf(w0, weA.x, x0A.x + xrA.x);
        float t1 = fmaf(w0, weA.y, x0A.y + xrA.y);
        float t2 = fmaf(w0, weA.z, x0A.z + xrA.z);
        float t3 = fmaf(w0, weA.w, x0A.w + xrA.w);
        float t4 = fmaf(w0, weB.x, x0B.x + xrB.x);
        float t5 = fmaf(w0, weB.y, x0B.y + xrB.y);
        float t6 = fmaf(w0, weB.z, x0B.z + xrB.z);
        float t7 = fmaf(w0, weB.w, x0B.w + xrB.w);
        t0 = fmaxf(t0, NEG_SLOPE * t0); t1 = fmaxf(t1, NEG_SLOPE * t1);
        t2 = fmaxf(t2, NEG_SLOPE * t2); t3 = fmaxf(t3, NEG_SLOPE * t3);
        t4 = fmaxf(t4, NEG_SLOPE * t4); t5 = fmaxf(t5, NEG_SLOPE * t5);
        t6 = fmaxf(t6, NEG_SLOPE * t6); t7 = fmaxf(t7, NEG_SLOPE * t7);
        float p0 = t0 * atA.x + t1 * atA.y + t2 * atA.z + t3 * atA.w
                 + t4 * atB.x + t5 * atB.y + t6 * atB.z + t7 * atB.w;
        float u0 = fmaf(w1, weA.x, x1A.x + xrA.x);
        float u1 = fmaf(w1, weA.y, x1A.y + xrA.y);
        float u2 = fmaf(w1, weA.z, x1A.z + xrA.z);
        float u3 = fmaf(w1, weA.w, x1A.w + xrA.w);
        float u4 = fmaf(w1, weB.x, x1B.x + xrB.x);
        float u5 = fmaf(w1, weB.y, x1B.y + xrB.y);
        float u6 = fmaf(w1, weB.z, x1B.z + xrB.z);
        float u7 = fmaf(w1, weB.w, x1B.w + xrB.w);
        u0 = fmaxf(u0, NEG_SLOPE * u0); u1 = fmaxf(u1, NEG_SLOPE * u1);
        u2 = fmaxf(u2, NEG_SLOPE * u2); u3 = fmaxf(u3, NEG_SLOPE * u3);
        u4 = fmaxf(u4, NEG_SLOPE * u4); u5 = fmaxf(u5, NEG_SLOPE * u5);
        u6 = fmaxf(u6, NEG_SLOPE * u6); u7 = fmaxf(u7, NEG_SLOPE * u7);
        float p1 = u0 * atA.x + u1 * atA.y + u2 * atA.z + u3 * atA.w
                 + u4 * atB.x + u5 * atB.y + u6 * atB.z + u7 * atB.w;
        p0 += __shfl_xor(p0, 1); p1 += __shfl_xor(p1, 1);
        p0 += __shfl_xor(p0, 2); p1 += __shfl_xor(p1, 2);
        p0 += __shfl_xor(p0, 4); p1 += __shfl_xor(p1, 4);
        float e0 = __expf(p0);
        float e1 = __expf(p1);
        e0 = v0 ? e0 : 0.f;
        e1 = v1 ? e1 : 0.f;
        den += e0 + e1;
        wacc += w0 + w1;
        a0 = fmaf(e0, x0A.x, fmaf(e1, x1A.x, a0));
        a1 = fmaf(e0, x0A.y, fmaf(e1, x1A.y, a1));
        a2 = fmaf(e0, x0A.z, fmaf(e1, x1A.z, a2));
        a3 = fmaf(e0, x0A.w, fmaf(e1, x1A.w, a3));
        a4 = fmaf(e0, x0B.x, fmaf(e1, x1B.x, a4));
        a5 = fmaf(e0, x0B.y, fmaf(e1, x1B.y, a5));
        a6 = fmaf(e0, x0B.z, fmaf(e1, x1B.z, a6));
        a7 = fmaf(e0, x0B.w, fmaf(e1, x1B.w, a7));
    }
#pragma unroll
    for (int off = 16; off <= 32; off <<= 1) {
        den += __shfl_xor(den, off);
        wacc += __shfl_xor(wacc, off);
        a0 += __shfl_xor(a0, off); a1 += __shfl_xor(a1, off);
        a2 += __shfl_xor(a2, off); a3 += __shfl_xor(a3, off);
        a4 += __shfl_xor(a4, off); a5 += __shfl_xor(a5, off);
        a6 += __shfl_xor(a6, off); a7 += __shfl_xor(a7, off);
    }
    // self-loop: weight = mean incoming edge weight, source feature = xl[n]
    {
        float lw = wacc / (float)max(deg, 1);
        const float* xp = xl + (size_t)n * 128 + d0;
        float4 xA = *(const float4*)xp;
        float4 xB = *(const float4*)(xp + 4);
        float t0 = fmaf(lw, weA.x, xA.x + xrA.x);
        float t1 = fmaf(lw, weA.y, xA.y + xrA.y);
        float t2 = fmaf(lw, weA.z, xA.z + xrA.z);
        float t3 = fmaf(lw, weA.w, xA.w + xrA.w);
        float t4 = fmaf(lw, weB.x, xB.x + xrB.x);
        float t5 = fmaf(lw, weB.y, xB.y + xrB.y);
        float t6 = fmaf(lw, weB.z, xB.z + xrB.z);
        float t7 = fmaf(lw, weB.w, xB.w + xrB.w);
        t0 = fmaxf(t0, NEG_SLOPE * t0); t1 = fmaxf(t1, NEG_SLOPE * t1);
        t2 = fmaxf(t2, NEG_SLOPE * t2); t3 = fmaxf(t3, NEG_SLOPE * t3);
        t4 = fmaxf(t4, NEG_SLOPE * t4); t5 = fmaxf(t5, NEG_SLOPE * t5);
        t6 = fmaxf(t6, NEG_SLOPE * t6); t7 = fmaxf(t7, NEG_SLOPE * t7);
        float p = t0 * atA.x + t1 * atA.y + t2 * atA.z + t3 * atA.w
                + t4 * atB.x + t5 * atB.y + t6 * atB.z + t7 * atB.w;
        p += __shfl_xor(p, 1);
        p += __shfl_xor(p, 2);
        p += __shfl_xor(p, 4);
        float e = __expf(p);
        den += e;
        a0 = fmaf(e, xA.x, a0); a1 = fmaf(e, xA.y, a1);
        a2 = fmaf(e, xA.z, a2); a3 = fmaf(e, xA.w, a3);
        a4 = fmaf(e, xB.x, a4); a5 = fmaf(e, xB.y, a5);
        a6 = fmaf(e, xB.z, a6); a7 = fmaf(e, xB.w, a7);
    }
    float inv = 1.f / den;
    float4 biA = *(const float4*)(bias + d0), biB = *(const float4*)(bias + d0 + 4);
    float o0 = a0 * inv + biA.x, o1 = a1 * inv + biA.y;
    float o2 = a2 * inv + biA.z, o3 = a3 * inv + biA.w;
    float o4 = a4 * inv + biB.x, o5 = a5 * inv + biB.y;
    float o6 = a6 * inv + biB.z, o7 = a7 * inv + biB.w;
    o0 = o0 > 0.f ? o0 : expm1f(o0); o1 = o1 > 0.f ? o1 : expm1f(o1);
    o2 = o2 > 0.f ? o2 : expm1f(o2); o3 = o3 > 0.f ? o3 : expm1f(o3);
    o4 = o4 > 0.f ? o4 : expm1f(o4); o5 = o5 > 0.f ? o5 : expm1f(o5);
    o6 = o6 > 0.f ? o6 : expm1f(o6); o7 = o7 > 0.f ? o7 : expm1f(o7);
    if (e4 == 0) {
        float* op = out + (size_t)n * 128 + d0;
        *(float4*)op       = make_float4(o0, o1, o2, o3);
        *(float4*)(op + 4) = make_float4(o4, o5, o6, o7);
    }
}

// ---------------- launch ----------------

extern "C" void kernel_launch(void* const* d_in, const int* in_sizes, int n_in,
                              void* d_out, int out_size, void* d_ws, size_t ws_size,
                              hipStream_t stream) {
    const int*   ei   = (const int*)d_in[0];
    const float* ew   = (const float*)d_in[1];
    const float* emb  = (const float*)d_in[2];
    const float* Wl   = (const float*)d_in[3];
    const float* Wr   = (const float*)d_in[4];
    const float* We   = (const float*)d_in[5];
    const float* att  = (const float*)d_in[6];
    const float* bias = (const float*)d_in[7];
    int E = in_sizes[1];
    int N = in_sizes[2] / 128;

    char* p = (char*)d_ws;
    auto alloc = [&](size_t bytes) { char* r = p; p += (bytes + 255) & ~(size_t)255; return r; };
    float* xl     = (float*)alloc((size_t)N * 128 * 4);
    float* xr     = (float*)alloc((size_t)N * 128 * 4);
    int2*  bucket = (int2*)alloc(((size_t)N * MAXDEG + 64) * 8);
    int*   cursor = (int*)alloc((size_t)N * 4);
    if ((size_t)(p - (char*)d_ws) > ws_size) return;   // workspace too small -> visible failure

    int ib = (N + 255) / 256;
    int fb = (E / 4 + 255) / 256;
    k_init<<<ib, 256, 0, stream>>>(cursor, N);
    k_fillb<<<fb, 256, 0, stream>>>(ei, ew, cursor, bucket, E);

    int gb = (N + 63) / 64;
    int nb = (N + 3) / 4;
    const float* h = emb;
    for (int l = 0; l < 2; ++l) {
        float* outl = (float*)d_out;               // layer0 result lives in d_out, re-read by layer1 gemm
        k_gemm<<<dim3(gb, 2), 256, 0, stream>>>(h, Wl + (size_t)l * 16384, Wr + (size_t)l * 16384, xl, xr, N);
        k_node<<<nb, 256, 0, stream>>>(xl, xr, cursor, bucket,
                                       We + (size_t)l * 128, att + (size_t)l * 128,
                                       bias + (size_t)l * 128, outl, N);
        h = outl;
    }
}

// Round 10
// 260.197 us; speedup vs baseline: 1.2975x; 1.1459x over previous
//
#include <hip/hip_runtime.h>
#include <cstdint>

#define NEG_SLOPE 0.2f
#define MAXDEG 64

typedef __attribute__((ext_vector_type(8))) short bf16x8;
typedef __attribute__((ext_vector_type(4))) float f32x4;

__device__ inline short bf16_rne(float x) {
    uint32_t u = __float_as_uint(x);
    return (short)((u + 0x7FFF + ((u >> 16) & 1)) >> 16);
}
__device__ inline float bf16_to_f32(short s) {
    uint32_t u = ((uint32_t)(uint16_t)s) << 16;
    return __uint_as_float(u);
}

// ---------------- bucketed CSR build: 1 atomic per edge, 4 edges/thread ----------------

__global__ __launch_bounds__(256) void k_init(int* __restrict__ cursor, int N) {
    int i = blockIdx.x * 256 + threadIdx.x;
    if (i < N) cursor[i] = i * MAXDEG;
}

__global__ __launch_bounds__(256) void k_fillb(const int* __restrict__ ei, const float* __restrict__ ew,
                                               int* __restrict__ cursor, int2* __restrict__ bucket, int E) {
    int i0 = (blockIdx.x * 256 + threadIdx.x) * 4;
    if (i0 >= E) return;
    if (i0 + 3 < E) {
        int4 s4 = *(const int4*)&ei[i0];
        int4 d4 = *(const int4*)&ei[E + i0];
        float4 w4 = *(const float4*)&ew[i0];
        int p0 = atomicAdd(&cursor[d4.x], 1);
        int p1 = atomicAdd(&cursor[d4.y], 1);
        int p2 = atomicAdd(&cursor[d4.z], 1);
        int p3 = atomicAdd(&cursor[d4.w], 1);
        bucket[p0] = make_int2(s4.x, __float_as_int(w4.x));
        bucket[p1] = make_int2(s4.y, __float_as_int(w4.y));
        bucket[p2] = make_int2(s4.z, __float_as_int(w4.z));
        bucket[p3] = make_int2(s4.w, __float_as_int(w4.w));
    } else {
        for (int i = i0; i < E; ++i) {
            int pos = atomicAdd(&cursor[ei[E + i]], 1);
            bucket[pos] = make_int2(ei[i], __float_as_int(ew[i]));
        }
    }
}

// ---------------- W pre-transform: Wt[n][k] bf16 hi/lo, chunked+padded for LDS copy ----------------
// wt layout: [l*2+mat][chunk 0..3]{ hi[128][40] | lo[128][40] }  (shorts)
__global__ __launch_bounds__(256) void k_cvtW(const float* __restrict__ Wl, const float* __restrict__ Wr,
                                              short* __restrict__ wt) {
    int b = blockIdx.x;             // 0..3 = (layer, mat)
    int l = b >> 1, mat = b & 1;
    const float* W = (mat ? Wr : Wl) + (size_t)l * 16384;
    short* dst = wt + (size_t)b * 40960;
    int t = threadIdx.x;
    int n = t >> 1, half = t & 1;   // n 0..127, half 0..1
    for (int chunk = 0; chunk < 4; ++chunk) {
        short hi16[16], lo16[16];
#pragma unroll
        for (int i = 0; i < 16; ++i) {
            int kk = half * 16 + i;
            float x = W[(size_t)(chunk * 32 + kk) * 128 + n];
            short h = bf16_rne(x);
            float r = x - bf16_to_f32(h);
            hi16[i] = h;
            lo16[i] = bf16_rne(r);
        }
        short* base = dst + chunk * 10240;
#pragma unroll
        for (int i = 0; i < 16; ++i) {
            base[n * 40 + half * 16 + i] = hi16[i];
            base[5120 + n * 40 + half * 16 + i] = lo16[i];
        }
    }
}

// ---------------- MFMA GEMM: O = H@W via split-bf16 (hi+lo), 64 rows/block ----------------
// blockIdx.y picks matrix (0: Wl->Ol, 1: Wr->Or). 3 passes: hi*Whi + lo*Whi + hi*Wlo.
__global__ __launch_bounds__(256) void k_gemm_mfma(const float* __restrict__ H, const short* __restrict__ wt,
                                                   float* __restrict__ Ol, float* __restrict__ Or, int N) {
    __shared__ __align__(16) short smem[2560 + 2560 + 10240]; // Ahi[64][40], Alo[64][40], W chunk hi|lo
    short* Ahi = smem;
    short* Alo = smem + 2560;
    short* Wst = smem + 5120;
    const short* wtm = wt + (size_t)blockIdx.y * 40960;
    float* O = blockIdx.y ? Or : Ol;
    int t = threadIdx.x;
    int w = t >> 6, lane = t & 63;
    int m = lane & 15, g = lane >> 4;
    int r0 = blockIdx.x * 64;
    f32x4 acc[8];
#pragma unroll
    for (int i = 0; i < 8; ++i) acc[i] = (f32x4){0.f, 0.f, 0.f, 0.f};

    int rr = t >> 2, q = t & 3;     // staging coords: row 0..63, quarter 0..3
    for (int chunk = 0; chunk < 4; ++chunk) {
        // stage W chunk (straight copy, 1280 16B units)
        const short* wsrc = wtm + chunk * 10240;
#pragma unroll
        for (int i = 0; i < 5; ++i) {
            int u = t + i * 256;
            *(int4*)&Wst[u * 8] = *(const int4*)&wsrc[u * 8];
        }
        // stage A chunk: read 8 f32 of H, split to bf16 hi/lo in-reg
        {
            int r = r0 + rr;
            float v[8];
            if (r < N) {
                float4 a = *(const float4*)&H[(size_t)r * 128 + chunk * 32 + q * 8];
                float4 b = *(const float4*)&H[(size_t)r * 128 + chunk * 32 + q * 8 + 4];
                v[0] = a.x; v[1] = a.y; v[2] = a.z; v[3] = a.w;
                v[4] = b.x; v[5] = b.y; v[6] = b.z; v[7] = b.w;
            } else {
#pragma unroll
                for (int i = 0; i < 8; ++i) v[i] = 0.f;
            }
            short hi8[8], lo8[8];
#pragma unroll
            for (int i = 0; i < 8; ++i) {
                short h = bf16_rne(v[i]);
                hi8[i] = h;
                lo8[i] = bf16_rne(v[i] - bf16_to_f32(h));
            }
            *(int4*)&Ahi[rr * 40 + q * 8] = *(int4*)hi8;
            *(int4*)&Alo[rr * 40 + q * 8] = *(int4*)lo8;
        }
        __syncthreads();
        bf16x8 ahi = *(bf16x8*)&Ahi[(w * 16 + m) * 40 + g * 8];
        bf16x8 alo = *(bf16x8*)&Alo[(w * 16 + m) * 40 + g * 8];
#pragma unroll
        for (int nf = 0; nf < 8; ++nf) {
            bf16x8 bhi = *(bf16x8*)&Wst[(nf * 16 + m) * 40 + g * 8];
            bf16x8 blo = *(bf16x8*)&Wst[5120 + (nf * 16 + m) * 40 + g * 8];
            acc[nf] = __builtin_amdgcn_mfma_f32_16x16x32_bf16(ahi, bhi, acc[nf], 0, 0, 0);
            acc[nf] = __builtin_amdgcn_mfma_f32_16x16x32_bf16(alo, bhi, acc[nf], 0, 0, 0);
            acc[nf] = __builtin_amdgcn_mfma_f32_16x16x32_bf16(ahi, blo, acc[nf], 0, 0, 0);
        }
        __syncthreads();
    }
    // epilogue: D[row=(g*4+j) within 16][col=m], row tile = w*16
#pragma unroll
    for (int nf = 0; nf < 8; ++nf) {
#pragma unroll
        for (int j = 0; j < 4; ++j) {
            int row = r0 + w * 16 + g * 4 + j;
            if (row < N) O[(size_t)row * 128 + nf * 16 + m] = acc[nf][j];
        }
    }
}

// ---------------- Node kernel: one wave per node, 8 edges in flight (2x4 paired) ----------------
__global__ __launch_bounds__(256) void k_node(const float* __restrict__ xl, const float* __restrict__ xr,
                                              const int* __restrict__ cursor, const int2* __restrict__ bucket,
                                              const float* __restrict__ We, const float* __restrict__ att,
                                              const float* __restrict__ bias, float* __restrict__ out, int N) {
    int wid = threadIdx.x >> 6;
    int lane = threadIdx.x & 63;
    int n = blockIdx.x * 4 + wid;
    if (n >= N) return;
    int sub = lane & 15, e4 = lane >> 4;
    int d0 = sub * 8;
    float4 weA = *(const float4*)(We + d0),  weB = *(const float4*)(We + d0 + 4);
    float4 atA = *(const float4*)(att + d0), atB = *(const float4*)(att + d0 + 4);
    const float* xrp = xr + (size_t)n * 128 + d0;
    float4 xrA = *(const float4*)xrp, xrB = *(const float4*)(xrp + 4);
    int beg = n * MAXDEG;
    int end = cursor[n];
    int deg = end - beg;
    int iters = (deg + 7) >> 3;
    float den = 0.f, wacc = 0.f;
    float a0 = 0.f, a1 = 0.f, a2 = 0.f, a3 = 0.f, a4 = 0.f, a5 = 0.f, a6 = 0.f, a7 = 0.f;
    for (int it = 0; it < iters; ++it) {
        int idx0 = beg + it * 8 + e4;
        int idx1 = idx0 + 4;
        bool v0 = idx0 < end, v1 = idx1 < end;
        int2 rec0 = bucket[idx0];
        int2 rec1 = bucket[idx1];
        int s0 = v0 ? rec0.x : n;
        int s1 = v1 ? rec1.x : n;
        float w0 = v0 ? __int_as_float(rec0.y) : 0.f;
        float w1 = v1 ? __int_as_float(rec1.y) : 0.f;
        const float* xp0 = xl + (size_t)s0 * 128 + d0;
        const float* xp1 = xl + (size_t)s1 * 128 + d0;
        float4 x0A = *(const float4*)xp0;
        float4 x0B = *(const float4*)(xp0 + 4);
        float4 x1A = *(const float4*)xp1;
        float4 x1B = *(const float4*)(xp1 + 4);
        float t0 = fmaf(w0, weA.x, x0A.x + xrA.x);
        float t1 = fmaf(w0, weA.y, x0A.y + xrA.y);
        float t2 = fmaf(w0, weA.z, x0A.z + xrA.z);
        float t3 = fmaf(w0, weA.w, x0A.w + xrA.w);
        float t4 = fmaf(w0, weB.x, x0B.x + xrB.x);
        float t5 = fmaf(w0, weB.y, x0B.y + xrB.y);
        float t6 = fmaf(w0, weB.z, x0B.z + xrB.z);
        float t7 = fmaf(w0, weB.w, x0B.w + xrB.w);
        t0 = fmaxf(t0, NEG_SLOPE * t0); t1 = fmaxf(t1, NEG_SLOPE * t1);
        t2 = fmaxf(t2, NEG_SLOPE * t2); t3 = fmaxf(t3, NEG_SLOPE * t3);
        t4 = fmaxf(t4, NEG_SLOPE * t4); t5 = fmaxf(t5, NEG_SLOPE * t5);
        t6 = fmaxf(t6, NEG_SLOPE * t6); t7 = fmaxf(t7, NEG_SLOPE * t7);
        float p0 = t0 * atA.x + t1 * atA.y + t2 * atA.z + t3 * atA.w
                 + t4 * atB.x + t5 * atB.y + t6 * atB.z + t7 * atB.w;
        float u0 = fmaf(w1, weA.x, x1A.x + xrA.x);
        float u1 = fmaf(w1, weA.y, x1A.y + xrA.y);
        float u2 = fmaf(w1, weA.z, x1A.z + xrA.z);
        float u3 = fmaf(w1, weA.w, x1A.w + xrA.w);
        float u4 = fmaf(w1, weB.x, x1B.x + xrB.x);
        float u5 = fmaf(w1, weB.y, x1B.y + xrB.y);
        float u6 = fmaf(w1, weB.z, x1B.z + xrB.z);
        float u7 = fmaf(w1, weB.w, x1B.w + xrB.w);
        u0 = fmaxf(u0, NEG_SLOPE * u0); u1 = fmaxf(u1, NEG_SLOPE * u1);
        u2 = fmaxf(u2, NEG_SLOPE * u2); u3 = fmaxf(u3, NEG_SLOPE * u3);
        u4 = fmaxf(u4, NEG_SLOPE * u4); u5 = fmaxf(u5, NEG_SLOPE * u5);
        u6 = fmaxf(u6, NEG_SLOPE * u6); u7 = fmaxf(u7, NEG_SLOPE * u7);
        float p1 = u0 * atA.x + u1 * atA.y + u2 * atA.z + u3 * atA.w
                 + u4 * atB.x + u5 * atB.y + u6 * atB.z + u7 * atB.w;
        p0 += __shfl_xor(p0, 1); p1 += __shfl_xor(p1, 1);
        p0 += __shfl_xor(p0, 2); p1 += __shfl_xor(p1, 2);
        p0 += __shfl_xor(p0, 4); p1 += __shfl_xor(p1, 4);
        float e0 = __expf(p0);
        float e1 = __expf(p1);
        e0 = v0 ? e0 : 0.f;
        e1 = v1 ? e1 : 0.f;
        den += e0 + e1;
        wacc += w0 + w1;
        a0 = fmaf(e0, x0A.x, fmaf(e1, x1A.x, a0));
        a1 = fmaf(e0, x0A.y, fmaf(e1, x1A.y, a1));
        a2 = fmaf(e0, x0A.z, fmaf(e1, x1A.z, a2));
        a3 = fmaf(e0, x0A.w, fmaf(e1, x1A.w, a3));
        a4 = fmaf(e0, x0B.x, fmaf(e1, x1B.x, a4));
        a5 = fmaf(e0, x0B.y, fmaf(e1, x1B.y, a5));
        a6 = fmaf(e0, x0B.z, fmaf(e1, x1B.z, a6));
        a7 = fmaf(e0, x0B.w, fmaf(e1, x1B.w, a7));
    }
#pragma unroll
    for (int off = 16; off <= 32; off <<= 1) {
        den += __shfl_xor(den, off);
        wacc += __shfl_xor(wacc, off);
        a0 += __shfl_xor(a0, off); a1 += __shfl_xor(a1, off);
        a2 += __shfl_xor(a2, off); a3 += __shfl_xor(a3, off);
        a4 += __shfl_xor(a4, off); a5 += __shfl_xor(a5, off);
        a6 += __shfl_xor(a6, off); a7 += __shfl_xor(a7, off);
    }
    // self-loop: weight = mean incoming edge weight, source feature = xl[n]
    {
        float lw = wacc / (float)max(deg, 1);
        const float* xp = xl + (size_t)n * 128 + d0;
        float4 xA = *(const float4*)xp;
        float4 xB = *(const float4*)(xp + 4);
        float t0 = fmaf(lw, weA.x, xA.x + xrA.x);
        float t1 = fmaf(lw, weA.y, xA.y + xrA.y);
        float t2 = fmaf(lw, weA.z, xA.z + xrA.z);
        float t3 = fmaf(lw, weA.w, xA.w + xrA.w);
        float t4 = fmaf(lw, weB.x, xB.x + xrB.x);
        float t5 = fmaf(lw, weB.y, xB.y + xrB.y);
        float t6 = fmaf(lw, weB.z, xB.z + xrB.z);
        float t7 = fmaf(lw, weB.w, xB.w + xrB.w);
        t0 = fmaxf(t0, NEG_SLOPE * t0); t1 = fmaxf(t1, NEG_SLOPE * t1);
        t2 = fmaxf(t2, NEG_SLOPE * t2); t3 = fmaxf(t3, NEG_SLOPE * t3);
        t4 = fmaxf(t4, NEG_SLOPE * t4); t5 = fmaxf(t5, NEG_SLOPE * t5);
        t6 = fmaxf(t6, NEG_SLOPE * t6); t7 = fmaxf(t7, NEG_SLOPE * t7);
        float p = t0 * atA.x + t1 * atA.y + t2 * atA.z + t3 * atA.w
                + t4 * atB.x + t5 * atB.y + t6 * atB.z + t7 * atB.w;
        p += __shfl_xor(p, 1);
        p += __shfl_xor(p, 2);
        p += __shfl_xor(p, 4);
        float e = __expf(p);
        den += e;
        a0 = fmaf(e, xA.x, a0); a1 = fmaf(e, xA.y, a1);
        a2 = fmaf(e, xA.z, a2); a3 = fmaf(e, xA.w, a3);
        a4 = fmaf(e, xB.x, a4); a5 = fmaf(e, xB.y, a5);
        a6 = fmaf(e, xB.z, a6); a7 = fmaf(e, xB.w, a7);
    }
    float inv = 1.f / den;
    float4 biA = *(const float4*)(bias + d0), biB = *(const float4*)(bias + d0 + 4);
    float o0 = a0 * inv + biA.x, o1 = a1 * inv + biA.y;
    float o2 = a2 * inv + biA.z, o3 = a3 * inv + biA.w;
    float o4 = a4 * inv + biB.x, o5 = a5 * inv + biB.y;
    float o6 = a6 * inv + biB.z, o7 = a7 * inv + biB.w;
    o0 = o0 > 0.f ? o0 : expm1f(o0); o1 = o1 > 0.f ? o1 : expm1f(o1);
    o2 = o2 > 0.f ? o2 : expm1f(o2); o3 = o3 > 0.f ? o3 : expm1f(o3);
    o4 = o4 > 0.f ? o4 : expm1f(o4); o5 = o5 > 0.f ? o5 : expm1f(o5);
    o6 = o6 > 0.f ? o6 : expm1f(o6); o7 = o7 > 0.f ? o7 : expm1f(o7);
    if (e4 == 0) {
        float* op = out + (size_t)n * 128 + d0;
        *(float4*)op       = make_float4(o0, o1, o2, o3);
        *(float4*)(op + 4) = make_float4(o4, o5, o6, o7);
    }
}

// ---------------- launch ----------------

extern "C" void kernel_launch(void* const* d_in, const int* in_sizes, int n_in,
                              void* d_out, int out_size, void* d_ws, size_t ws_size,
                              hipStream_t stream) {
    const int*   ei   = (const int*)d_in[0];
    const float* ew   = (const float*)d_in[1];
    const float* emb  = (const float*)d_in[2];
    const float* Wl   = (const float*)d_in[3];
    const float* Wr   = (const float*)d_in[4];
    const float* We   = (const float*)d_in[5];
    const float* att  = (const float*)d_in[6];
    const float* bias = (const float*)d_in[7];
    int E = in_sizes[1];
    int N = in_sizes[2] / 128;

    char* p = (char*)d_ws;
    auto alloc = [&](size_t bytes) { char* r = p; p += (bytes + 255) & ~(size_t)255; return r; };
    float* xl     = (float*)alloc((size_t)N * 128 * 4);
    float* xr     = (float*)alloc((size_t)N * 128 * 4);
    int2*  bucket = (int2*)alloc(((size_t)N * MAXDEG + 64) * 8);
    int*   cursor = (int*)alloc((size_t)N * 4);
    short* wtbuf  = (short*)alloc((size_t)4 * 40960 * 2);    // 4 (l,mat) x 40960 shorts
    if ((size_t)(p - (char*)d_ws) > ws_size) return;         // visible failure if ws too small

    int ib = (N + 255) / 256;
    int fb = (E / 4 + 255) / 256;
    k_init<<<ib, 256, 0, stream>>>(cursor, N);
    k_fillb<<<fb, 256, 0, stream>>>(ei, ew, cursor, bucket, E);
    k_cvtW<<<4, 256, 0, stream>>>(Wl, Wr, wtbuf);

    int gb = (N + 63) / 64;
    int nb = (N + 3) / 4;
    const float* h = emb;
    for (int l = 0; l < 2; ++l) {
        float* outl = (float*)d_out;   // layer0 result lives in d_out, re-read by layer1 gemm
        k_gemm_mfma<<<dim3(gb, 2), 256, 0, stream>>>(h, wtbuf + (size_t)l * 81920, xl, xr, N);
        k_node<<<nb, 256, 0, stream>>>(xl, xr, cursor, bucket,
                                       We + (size_t)l * 128, att + (size_t)l * 128,
                                       bias + (size_t)l * 128, outl, N);
        h = outl;
    }
}

// Round 11
// 249.429 us; speedup vs baseline: 1.3535x; 1.0432x over previous
//
#include <hip/hip_runtime.h>
#include <cstdint>

#define NEG_SLOPE 0.2f
#define MAXDEG 64

typedef __attribute__((ext_vector_type(8))) short bf16x8;
typedef __attribute__((ext_vector_type(4))) float f32x4;

__device__ inline short bf16_rne(float x) {
    uint32_t u = __float_as_uint(x);
    return (short)((u + 0x7FFF + ((u >> 16) & 1)) >> 16);
}
__device__ inline float bf16_to_f32(short s) {
    uint32_t u = ((uint32_t)(uint16_t)s) << 16;
    return __uint_as_float(u);
}

// ---------------- bucketed CSR build: 1 atomic per edge, 8 edges/thread ----------------

__global__ __launch_bounds__(256) void k_init(int* __restrict__ cursor, int N) {
    int i = blockIdx.x * 256 + threadIdx.x;
    if (i < N) cursor[i] = i * MAXDEG;
}

__global__ __launch_bounds__(256) void k_fillb(const int* __restrict__ ei, const float* __restrict__ ew,
                                               int* __restrict__ cursor, int2* __restrict__ bucket, int E) {
    int i0 = (blockIdx.x * 256 + threadIdx.x) * 8;
    if (i0 >= E) return;
    if (i0 + 7 < E) {
        int4 sa = *(const int4*)&ei[i0];
        int4 sb = *(const int4*)&ei[i0 + 4];
        int4 da = *(const int4*)&ei[E + i0];
        int4 db = *(const int4*)&ei[E + i0 + 4];
        float4 wa = *(const float4*)&ew[i0];
        float4 wb = *(const float4*)&ew[i0 + 4];
        int p0 = atomicAdd(&cursor[da.x], 1);
        int p1 = atomicAdd(&cursor[da.y], 1);
        int p2 = atomicAdd(&cursor[da.z], 1);
        int p3 = atomicAdd(&cursor[da.w], 1);
        int p4 = atomicAdd(&cursor[db.x], 1);
        int p5 = atomicAdd(&cursor[db.y], 1);
        int p6 = atomicAdd(&cursor[db.z], 1);
        int p7 = atomicAdd(&cursor[db.w], 1);
        bucket[p0] = make_int2(sa.x, __float_as_int(wa.x));
        bucket[p1] = make_int2(sa.y, __float_as_int(wa.y));
        bucket[p2] = make_int2(sa.z, __float_as_int(wa.z));
        bucket[p3] = make_int2(sa.w, __float_as_int(wa.w));
        bucket[p4] = make_int2(sb.x, __float_as_int(wb.x));
        bucket[p5] = make_int2(sb.y, __float_as_int(wb.y));
        bucket[p6] = make_int2(sb.z, __float_as_int(wb.z));
        bucket[p7] = make_int2(sb.w, __float_as_int(wb.w));
    } else {
        for (int i = i0; i < E; ++i) {
            int pos = atomicAdd(&cursor[ei[E + i]], 1);
            bucket[pos] = make_int2(ei[i], __float_as_int(ew[i]));
        }
    }
}

// ---------------- W pre-transform: Wt[n][k] bf16 hi/lo, chunked+padded for LDS copy ----------------
__global__ __launch_bounds__(256) void k_cvtW(const float* __restrict__ Wl, const float* __restrict__ Wr,
                                              short* __restrict__ wt) {
    int b = blockIdx.x;             // 0..3 = (layer, mat)
    int l = b >> 1, mat = b & 1;
    const float* W = (mat ? Wr : Wl) + (size_t)l * 16384;
    short* dst = wt + (size_t)b * 40960;
    int t = threadIdx.x;
    int n = t >> 1, half = t & 1;   // n 0..127, half 0..1
    for (int chunk = 0; chunk < 4; ++chunk) {
        short hi16[16], lo16[16];
#pragma unroll
        for (int i = 0; i < 16; ++i) {
            int kk = half * 16 + i;
            float x = W[(size_t)(chunk * 32 + kk) * 128 + n];
            short h = bf16_rne(x);
            float r = x - bf16_to_f32(h);
            hi16[i] = h;
            lo16[i] = bf16_rne(r);
        }
        short* base = dst + chunk * 10240;
#pragma unroll
        for (int i = 0; i < 16; ++i) {
            base[n * 40 + half * 16 + i] = hi16[i];
            base[5120 + n * 40 + half * 16 + i] = lo16[i];
        }
    }
}

// ---------------- MFMA GEMM: O = H@W via split-bf16 (hi+lo), 64 rows/block ----------------
__global__ __launch_bounds__(256) void k_gemm_mfma(const float* __restrict__ H, const short* __restrict__ wt,
                                                   float* __restrict__ Ol, float* __restrict__ Or, int N) {
    __shared__ __align__(16) short smem[2560 + 2560 + 10240]; // Ahi[64][40], Alo[64][40], W chunk hi|lo
    short* Ahi = smem;
    short* Alo = smem + 2560;
    short* Wst = smem + 5120;
    const short* wtm = wt + (size_t)blockIdx.y * 40960;
    float* O = blockIdx.y ? Or : Ol;
    int t = threadIdx.x;
    int w = t >> 6, lane = t & 63;
    int m = lane & 15, g = lane >> 4;
    int r0 = blockIdx.x * 64;
    f32x4 acc[8];
#pragma unroll
    for (int i = 0; i < 8; ++i) acc[i] = (f32x4){0.f, 0.f, 0.f, 0.f};

    int rr = t >> 2, q = t & 3;     // staging coords: row 0..63, quarter 0..3
    for (int chunk = 0; chunk < 4; ++chunk) {
        const short* wsrc = wtm + chunk * 10240;
#pragma unroll
        for (int i = 0; i < 5; ++i) {
            int u = t + i * 256;
            *(int4*)&Wst[u * 8] = *(const int4*)&wsrc[u * 8];
        }
        {
            int r = r0 + rr;
            float v[8];
            if (r < N) {
                float4 a = *(const float4*)&H[(size_t)r * 128 + chunk * 32 + q * 8];
                float4 b = *(const float4*)&H[(size_t)r * 128 + chunk * 32 + q * 8 + 4];
                v[0] = a.x; v[1] = a.y; v[2] = a.z; v[3] = a.w;
                v[4] = b.x; v[5] = b.y; v[6] = b.z; v[7] = b.w;
            } else {
#pragma unroll
                for (int i = 0; i < 8; ++i) v[i] = 0.f;
            }
            short hi8[8], lo8[8];
#pragma unroll
            for (int i = 0; i < 8; ++i) {
                short h = bf16_rne(v[i]);
                hi8[i] = h;
                lo8[i] = bf16_rne(v[i] - bf16_to_f32(h));
            }
            *(int4*)&Ahi[rr * 40 + q * 8] = *(int4*)hi8;
            *(int4*)&Alo[rr * 40 + q * 8] = *(int4*)lo8;
        }
        __syncthreads();
        bf16x8 ahi = *(bf16x8*)&Ahi[(w * 16 + m) * 40 + g * 8];
        bf16x8 alo = *(bf16x8*)&Alo[(w * 16 + m) * 40 + g * 8];
#pragma unroll
        for (int nf = 0; nf < 8; ++nf) {
            bf16x8 bhi = *(bf16x8*)&Wst[(nf * 16 + m) * 40 + g * 8];
            bf16x8 blo = *(bf16x8*)&Wst[5120 + (nf * 16 + m) * 40 + g * 8];
            acc[nf] = __builtin_amdgcn_mfma_f32_16x16x32_bf16(ahi, bhi, acc[nf], 0, 0, 0);
            acc[nf] = __builtin_amdgcn_mfma_f32_16x16x32_bf16(alo, bhi, acc[nf], 0, 0, 0);
            acc[nf] = __builtin_amdgcn_mfma_f32_16x16x32_bf16(ahi, blo, acc[nf], 0, 0, 0);
        }
        __syncthreads();
    }
#pragma unroll
    for (int nf = 0; nf < 8; ++nf) {
#pragma unroll
        for (int j = 0; j < 4; ++j) {
            int row = r0 + w * 16 + g * 4 + j;
            if (row < N) O[(size_t)row * 128 + nf * 16 + m] = acc[nf][j];
        }
    }
}

// ---------------- Node kernel: whole bucket row in 1 coalesced load + bpermute, ----------------
// ---------------- software-pipelined xl gathers (ping-pong P/Q register sets) ----------------
// STAGE(it): distribute slot records via ds_bpermute, issue 4 b128 xl loads.
// CONSUME: score + exp + accumulate for the 2 edges of the staged set.

#define STAGE(IT, X0A, X0B, X1A, X1B, W0, W1, V0, V1)                          \
    {                                                                          \
        int slot0 = (IT) * 8 + e4;                                             \
        int slot1 = slot0 + 4;                                                 \
        int s0i = __builtin_amdgcn_ds_bpermute(slot0 << 2, recAll.x);          \
        int w0i = __builtin_amdgcn_ds_bpermute(slot0 << 2, recAll.y);          \
        int s1i = __builtin_amdgcn_ds_bpermute(slot1 << 2, recAll.x);          \
        int w1i = __builtin_amdgcn_ds_bpermute(slot1 << 2, recAll.y);          \
        V0 = slot0 < deg; V1 = slot1 < deg;                                    \
        int off0 = ((V0 ? s0i : n) << 7) + d0;                                 \
        int off1 = ((V1 ? s1i : n) << 7) + d0;                                 \
        W0 = V0 ? __int_as_float(w0i) : 0.f;                                   \
        W1 = V1 ? __int_as_float(w1i) : 0.f;                                   \
        X0A = *(const float4*)(xl + off0);                                     \
        X0B = *(const float4*)(xl + off0 + 4);                                 \
        X1A = *(const float4*)(xl + off1);                                     \
        X1B = *(const float4*)(xl + off1 + 4);                                 \
    }

#define CONSUME(X0A, X0B, X1A, X1B, W0, W1, V0, V1)                            \
    {                                                                          \
        float t0 = fmaf(W0, weA.x, X0A.x + xrA.x);                             \
        float t1 = fmaf(W0, weA.y, X0A.y + xrA.y);                             \
        float t2 = fmaf(W0, weA.z, X0A.z + xrA.z);                             \
        float t3 = fmaf(W0, weA.w, X0A.w + xrA.w);                             \
        float t4 = fmaf(W0, weB.x, X0B.x + xrB.x);                             \
        float t5 = fmaf(W0, weB.y, X0B.y + xrB.y);                             \
        float t6 = fmaf(W0, weB.z, X0B.z + xrB.z);                             \
        float t7 = fmaf(W0, weB.w, X0B.w + xrB.w);                             \
        t0 = fmaxf(t0, NEG_SLOPE * t0); t1 = fmaxf(t1, NEG_SLOPE * t1);        \
        t2 = fmaxf(t2, NEG_SLOPE * t2); t3 = fmaxf(t3, NEG_SLOPE * t3);        \
        t4 = fmaxf(t4, NEG_SLOPE * t4); t5 = fmaxf(t5, NEG_SLOPE * t5);        \
        t6 = fmaxf(t6, NEG_SLOPE * t6); t7 = fmaxf(t7, NEG_SLOPE * t7);        \
        float p0 = t0 * atA.x + t1 * atA.y + t2 * atA.z + t3 * atA.w           \
                 + t4 * atB.x + t5 * atB.y + t6 * atB.z + t7 * atB.w;          \
        float u0 = fmaf(W1, weA.x, X1A.x + xrA.x);                             \
        float u1 = fmaf(W1, weA.y, X1A.y + xrA.y);                             \
        float u2 = fmaf(W1, weA.z, X1A.z + xrA.z);                             \
        float u3 = fmaf(W1, weA.w, X1A.w + xrA.w);                             \
        float u4 = fmaf(W1, weB.x, X1B.x + xrB.x);                             \
        float u5 = fmaf(W1, weB.y, X1B.y + xrB.y);                             \
        float u6 = fmaf(W1, weB.z, X1B.z + xrB.z);                             \
        float u7 = fmaf(W1, weB.w, X1B.w + xrB.w);                             \
        u0 = fmaxf(u0, NEG_SLOPE * u0); u1 = fmaxf(u1, NEG_SLOPE * u1);        \
        u2 = fmaxf(u2, NEG_SLOPE * u2); u3 = fmaxf(u3, NEG_SLOPE * u3);        \
        u4 = fmaxf(u4, NEG_SLOPE * u4); u5 = fmaxf(u5, NEG_SLOPE * u5);        \
        u6 = fmaxf(u6, NEG_SLOPE * u6); u7 = fmaxf(u7, NEG_SLOPE * u7);        \
        float p1 = u0 * atA.x + u1 * atA.y + u2 * atA.z + u3 * atA.w           \
                 + u4 * atB.x + u5 * atB.y + u6 * atB.z + u7 * atB.w;          \
        p0 += __shfl_xor(p0, 1); p1 += __shfl_xor(p1, 1);                      \
        p0 += __shfl_xor(p0, 2); p1 += __shfl_xor(p1, 2);                      \
        p0 += __shfl_xor(p0, 4); p1 += __shfl_xor(p1, 4);                      \
        float e0 = __expf(p0);                                                 \
        float e1 = __expf(p1);                                                 \
        e0 = V0 ? e0 : 0.f;                                                    \
        e1 = V1 ? e1 : 0.f;                                                    \
        den += e0 + e1;                                                        \
        wacc += W0 + W1;                                                       \
        a0 = fmaf(e0, X0A.x, fmaf(e1, X1A.x, a0));                             \
        a1 = fmaf(e0, X0A.y, fmaf(e1, X1A.y, a1));                             \
        a2 = fmaf(e0, X0A.z, fmaf(e1, X1A.z, a2));                             \
        a3 = fmaf(e0, X0A.w, fmaf(e1, X1A.w, a3));                             \
        a4 = fmaf(e0, X0B.x, fmaf(e1, X1B.x, a4));                             \
        a5 = fmaf(e0, X0B.y, fmaf(e1, X1B.y, a5));                             \
        a6 = fmaf(e0, X0B.z, fmaf(e1, X1B.z, a6));                             \
        a7 = fmaf(e0, X0B.w, fmaf(e1, X1B.w, a7));                             \
    }

__global__ __launch_bounds__(256) void k_node(const float* __restrict__ xl, const float* __restrict__ xr,
                                              const int* __restrict__ cursor, const int2* __restrict__ bucket,
                                              const float* __restrict__ We, const float* __restrict__ att,
                                              const float* __restrict__ bias, float* __restrict__ out, int N) {
    int wid = threadIdx.x >> 6;
    int lane = threadIdx.x & 63;
    int n = blockIdx.x * 4 + wid;
    if (n >= N) return;
    int sub = lane & 15, e4 = lane >> 4;
    int d0 = sub * 8;
    float4 weA = *(const float4*)(We + d0),  weB = *(const float4*)(We + d0 + 4);
    float4 atA = *(const float4*)(att + d0), atB = *(const float4*)(att + d0 + 4);
    const float* xrp = xr + n * 128 + d0;
    float4 xrA = *(const float4*)xrp, xrB = *(const float4*)(xrp + 4);
    int beg = n * MAXDEG;
    int deg = cursor[n] - beg;
    int iters = (deg + 7) >> 3;
    int2 recAll = bucket[beg + lane];            // whole bucket row, one coalesced load
    float den = 0.f, wacc = 0.f;
    float a0 = 0.f, a1 = 0.f, a2 = 0.f, a3 = 0.f, a4 = 0.f, a5 = 0.f, a6 = 0.f, a7 = 0.f;

    float4 pX0A, pX0B, pX1A, pX1B; float pW0, pW1; bool pV0, pV1;
    float4 qX0A, qX0B, qX1A, qX1B; float qW0, qW1; bool qV0, qV1;
    STAGE(0, pX0A, pX0B, pX1A, pX1B, pW0, pW1, pV0, pV1);
    for (int it = 0; it < iters; ) {             // all branches wave-uniform (same n)
        if (it + 1 < iters) STAGE(it + 1, qX0A, qX0B, qX1A, qX1B, qW0, qW1, qV0, qV1);
        CONSUME(pX0A, pX0B, pX1A, pX1B, pW0, pW1, pV0, pV1);
        ++it;
        if (it >= iters) break;
        if (it + 1 < iters) STAGE(it + 1, pX0A, pX0B, pX1A, pX1B, pW0, pW1, pV0, pV1);
        CONSUME(qX0A, qX0B, qX1A, qX1B, qW0, qW1, qV0, qV1);
        ++it;
    }
#pragma unroll
    for (int off = 16; off <= 32; off <<= 1) {
        den += __shfl_xor(den, off);
        wacc += __shfl_xor(wacc, off);
        a0 += __shfl_xor(a0, off); a1 += __shfl_xor(a1, off);
        a2 += __shfl_xor(a2, off); a3 += __shfl_xor(a3, off);
        a4 += __shfl_xor(a4, off); a5 += __shfl_xor(a5, off);
        a6 += __shfl_xor(a6, off); a7 += __shfl_xor(a7, off);
    }
    // self-loop: weight = mean incoming edge weight, source feature = xl[n]
    {
        float lw = wacc / (float)max(deg, 1);
        const float* xp = xl + n * 128 + d0;
        float4 xA = *(const float4*)xp;
        float4 xB = *(const float4*)(xp + 4);
        float t0 = fmaf(lw, weA.x, xA.x + xrA.x);
        float t1 = fmaf(lw, weA.y, xA.y + xrA.y);
        float t2 = fmaf(lw, weA.z, xA.z + xrA.z);
        float t3 = fmaf(lw, weA.w, xA.w + xrA.w);
        float t4 = fmaf(lw, weB.x, xB.x + xrB.x);
        float t5 = fmaf(lw, weB.y, xB.y + xrB.y);
        float t6 = fmaf(lw, weB.z, xB.z + xrB.z);
        float t7 = fmaf(lw, weB.w, xB.w + xrB.w);
        t0 = fmaxf(t0, NEG_SLOPE * t0); t1 = fmaxf(t1, NEG_SLOPE * t1);
        t2 = fmaxf(t2, NEG_SLOPE * t2); t3 = fmaxf(t3, NEG_SLOPE * t3);
        t4 = fmaxf(t4, NEG_SLOPE * t4); t5 = fmaxf(t5, NEG_SLOPE * t5);
        t6 = fmaxf(t6, NEG_SLOPE * t6); t7 = fmaxf(t7, NEG_SLOPE * t7);
        float p = t0 * atA.x + t1 * atA.y + t2 * atA.z + t3 * atA.w
                + t4 * atB.x + t5 * atB.y + t6 * atB.z + t7 * atB.w;
        p += __shfl_xor(p, 1);
        p += __shfl_xor(p, 2);
        p += __shfl_xor(p, 4);
        float e = __expf(p);
        den += e;
        a0 = fmaf(e, xA.x, a0); a1 = fmaf(e, xA.y, a1);
        a2 = fmaf(e, xA.z, a2); a3 = fmaf(e, xA.w, a3);
        a4 = fmaf(e, xB.x, a4); a5 = fmaf(e, xB.y, a5);
        a6 = fmaf(e, xB.z, a6); a7 = fmaf(e, xB.w, a7);
    }
    float inv = 1.f / den;
    float4 biA = *(const float4*)(bias + d0), biB = *(const float4*)(bias + d0 + 4);
    float o0 = a0 * inv + biA.x, o1 = a1 * inv + biA.y;
    float o2 = a2 * inv + biA.z, o3 = a3 * inv + biA.w;
    float o4 = a4 * inv + biB.x, o5 = a5 * inv + biB.y;
    float o6 = a6 * inv + biB.z, o7 = a7 * inv + biB.w;
    o0 = o0 > 0.f ? o0 : expm1f(o0); o1 = o1 > 0.f ? o1 : expm1f(o1);
    o2 = o2 > 0.f ? o2 : expm1f(o2); o3 = o3 > 0.f ? o3 : expm1f(o3);
    o4 = o4 > 0.f ? o4 : expm1f(o4); o5 = o5 > 0.f ? o5 : expm1f(o5);
    o6 = o6 > 0.f ? o6 : expm1f(o6); o7 = o7 > 0.f ? o7 : expm1f(o7);
    if (e4 == 0) {
        float* op = out + n * 128 + d0;
        *(float4*)op       = make_float4(o0, o1, o2, o3);
        *(float4*)(op + 4) = make_float4(o4, o5, o6, o7);
    }
}

// ---------------- launch ----------------

extern "C" void kernel_launch(void* const* d_in, const int* in_sizes, int n_in,
                              void* d_out, int out_size, void* d_ws, size_t ws_size,
                              hipStream_t stream) {
    const int*   ei   = (const int*)d_in[0];
    const float* ew   = (const float*)d_in[1];
    const float* emb  = (const float*)d_in[2];
    const float* Wl   = (const float*)d_in[3];
    const float* Wr   = (const float*)d_in[4];
    const float* We   = (const float*)d_in[5];
    const float* att  = (const float*)d_in[6];
    const float* bias = (const float*)d_in[7];
    int E = in_sizes[1];
    int N = in_sizes[2] / 128;

    char* p = (char*)d_ws;
    auto alloc = [&](size_t bytes) { char* r = p; p += (bytes + 255) & ~(size_t)255; return r; };
    float* xl     = (float*)alloc((size_t)N * 128 * 4);
    float* xr     = (float*)alloc((size_t)N * 128 * 4);
    int2*  bucket = (int2*)alloc(((size_t)N * MAXDEG + 64) * 8);
    int*   cursor = (int*)alloc((size_t)N * 4);
    short* wtbuf  = (short*)alloc((size_t)4 * 40960 * 2);
    if ((size_t)(p - (char*)d_ws) > ws_size) return;

    int ib = (N + 255) / 256;
    int fb = (E / 8 + 255) / 256;
    k_init<<<ib, 256, 0, stream>>>(cursor, N);
    k_fillb<<<fb, 256, 0, stream>>>(ei, ew, cursor, bucket, E);
    k_cvtW<<<4, 256, 0, stream>>>(Wl, Wr, wtbuf);

    int gb = (N + 63) / 64;
    int nb = (N + 3) / 4;
    const float* h = emb;
    for (int l = 0; l < 2; ++l) {
        float* outl = (float*)d_out;   // layer0 result lives in d_out, re-read by layer1 gemm
        k_gemm_mfma<<<dim3(gb, 2), 256, 0, stream>>>(h, wtbuf + (size_t)l * 81920, xl, xr, N);
        k_node<<<nb, 256, 0, stream>>>(xl, xr, cursor, bucket,
                                       We + (size_t)l * 128, att + (size_t)l * 128,
                                       bias + (size_t)l * 128, outl, N);
        h = outl;
    }
}

// Round 12
// 231.228 us; speedup vs baseline: 1.4600x; 1.0787x over previous
//
#include <hip/hip_runtime.h>
#include <hip/hip_fp16.h>
#include <cstdint>

#define NEG_SLOPE 0.2f
#define MAXDEG 64

typedef __attribute__((ext_vector_type(8))) short bf16x8;
typedef __attribute__((ext_vector_type(4))) float f32x4;

__device__ inline short bf16_rne(float x) {
    uint32_t u = __float_as_uint(x);
    return (short)((u + 0x7FFF + ((u >> 16) & 1)) >> 16);
}
__device__ inline float bf16_to_f32(short s) {
    uint32_t u = ((uint32_t)(uint16_t)s) << 16;
    return __uint_as_float(u);
}

// ---------------- bucketed CSR build: 1 atomic per edge, 8 edges/thread ----------------

__global__ __launch_bounds__(256) void k_init(int* __restrict__ cursor, int N) {
    int i = blockIdx.x * 256 + threadIdx.x;
    if (i < N) cursor[i] = i * MAXDEG;
}

__global__ __launch_bounds__(256) void k_fillb(const int* __restrict__ ei, const float* __restrict__ ew,
                                               int* __restrict__ cursor, int2* __restrict__ bucket, int E) {
    int i0 = (blockIdx.x * 256 + threadIdx.x) * 8;
    if (i0 >= E) return;
    if (i0 + 7 < E) {
        int4 sa = *(const int4*)&ei[i0];
        int4 sb = *(const int4*)&ei[i0 + 4];
        int4 da = *(const int4*)&ei[E + i0];
        int4 db = *(const int4*)&ei[E + i0 + 4];
        float4 wa = *(const float4*)&ew[i0];
        float4 wb = *(const float4*)&ew[i0 + 4];
        int p0 = atomicAdd(&cursor[da.x], 1);
        int p1 = atomicAdd(&cursor[da.y], 1);
        int p2 = atomicAdd(&cursor[da.z], 1);
        int p3 = atomicAdd(&cursor[da.w], 1);
        int p4 = atomicAdd(&cursor[db.x], 1);
        int p5 = atomicAdd(&cursor[db.y], 1);
        int p6 = atomicAdd(&cursor[db.z], 1);
        int p7 = atomicAdd(&cursor[db.w], 1);
        bucket[p0] = make_int2(sa.x, __float_as_int(wa.x));
        bucket[p1] = make_int2(sa.y, __float_as_int(wa.y));
        bucket[p2] = make_int2(sa.z, __float_as_int(wa.z));
        bucket[p3] = make_int2(sa.w, __float_as_int(wa.w));
        bucket[p4] = make_int2(sb.x, __float_as_int(wb.x));
        bucket[p5] = make_int2(sb.y, __float_as_int(wb.y));
        bucket[p6] = make_int2(sb.z, __float_as_int(wb.z));
        bucket[p7] = make_int2(sb.w, __float_as_int(wb.w));
    } else {
        for (int i = i0; i < E; ++i) {
            int pos = atomicAdd(&cursor[ei[E + i]], 1);
            bucket[pos] = make_int2(ei[i], __float_as_int(ew[i]));
        }
    }
}

// ---------------- W pre-transform: Wt[n][k] bf16 hi/lo, chunked+padded for LDS copy ----------------
__global__ __launch_bounds__(256) void k_cvtW(const float* __restrict__ Wl, const float* __restrict__ Wr,
                                              short* __restrict__ wt) {
    int b = blockIdx.x;             // 0..3 = (layer, mat)
    int l = b >> 1, mat = b & 1;
    const float* W = (mat ? Wr : Wl) + (size_t)l * 16384;
    short* dst = wt + (size_t)b * 40960;
    int t = threadIdx.x;
    int n = t >> 1, half = t & 1;   // n 0..127, half 0..1
    for (int chunk = 0; chunk < 4; ++chunk) {
        short hi16[16], lo16[16];
#pragma unroll
        for (int i = 0; i < 16; ++i) {
            int kk = half * 16 + i;
            float x = W[(size_t)(chunk * 32 + kk) * 128 + n];
            short h = bf16_rne(x);
            float r = x - bf16_to_f32(h);
            hi16[i] = h;
            lo16[i] = bf16_rne(r);
        }
        short* base = dst + chunk * 10240;
#pragma unroll
        for (int i = 0; i < 16; ++i) {
            base[n * 40 + half * 16 + i] = hi16[i];
            base[5120 + n * 40 + half * 16 + i] = lo16[i];
        }
    }
}

// ---------------- MFMA GEMM: O = H@W via split-bf16 (hi+lo), 64 rows/block ----------------
// blockIdx.y==0: output fp16 (xl, gathered by k_node). blockIdx.y==1: output f32 (xr).
__global__ __launch_bounds__(256) void k_gemm_mfma(const float* __restrict__ H, const short* __restrict__ wt,
                                                   __half* __restrict__ Olh, float* __restrict__ Or, int N) {
    __shared__ __align__(16) short smem[2560 + 2560 + 10240]; // Ahi[64][40], Alo[64][40], W chunk hi|lo
    short* Ahi = smem;
    short* Alo = smem + 2560;
    short* Wst = smem + 5120;
    const short* wtm = wt + (size_t)blockIdx.y * 40960;
    int t = threadIdx.x;
    int w = t >> 6, lane = t & 63;
    int m = lane & 15, g = lane >> 4;
    int r0 = blockIdx.x * 64;
    f32x4 acc[8];
#pragma unroll
    for (int i = 0; i < 8; ++i) acc[i] = (f32x4){0.f, 0.f, 0.f, 0.f};

    int rr = t >> 2, q = t & 3;     // staging coords: row 0..63, quarter 0..3
    for (int chunk = 0; chunk < 4; ++chunk) {
        const short* wsrc = wtm + chunk * 10240;
#pragma unroll
        for (int i = 0; i < 5; ++i) {
            int u = t + i * 256;
            *(int4*)&Wst[u * 8] = *(const int4*)&wsrc[u * 8];
        }
        {
            int r = r0 + rr;
            float v[8];
            if (r < N) {
                float4 a = *(const float4*)&H[(size_t)r * 128 + chunk * 32 + q * 8];
                float4 b = *(const float4*)&H[(size_t)r * 128 + chunk * 32 + q * 8 + 4];
                v[0] = a.x; v[1] = a.y; v[2] = a.z; v[3] = a.w;
                v[4] = b.x; v[5] = b.y; v[6] = b.z; v[7] = b.w;
            } else {
#pragma unroll
                for (int i = 0; i < 8; ++i) v[i] = 0.f;
            }
            short hi8[8], lo8[8];
#pragma unroll
            for (int i = 0; i < 8; ++i) {
                short h = bf16_rne(v[i]);
                hi8[i] = h;
                lo8[i] = bf16_rne(v[i] - bf16_to_f32(h));
            }
            *(int4*)&Ahi[rr * 40 + q * 8] = *(int4*)hi8;
            *(int4*)&Alo[rr * 40 + q * 8] = *(int4*)lo8;
        }
        __syncthreads();
        bf16x8 ahi = *(bf16x8*)&Ahi[(w * 16 + m) * 40 + g * 8];
        bf16x8 alo = *(bf16x8*)&Alo[(w * 16 + m) * 40 + g * 8];
#pragma unroll
        for (int nf = 0; nf < 8; ++nf) {
            bf16x8 bhi = *(bf16x8*)&Wst[(nf * 16 + m) * 40 + g * 8];
            bf16x8 blo = *(bf16x8*)&Wst[5120 + (nf * 16 + m) * 40 + g * 8];
            acc[nf] = __builtin_amdgcn_mfma_f32_16x16x32_bf16(ahi, bhi, acc[nf], 0, 0, 0);
            acc[nf] = __builtin_amdgcn_mfma_f32_16x16x32_bf16(alo, bhi, acc[nf], 0, 0, 0);
            acc[nf] = __builtin_amdgcn_mfma_f32_16x16x32_bf16(ahi, blo, acc[nf], 0, 0, 0);
        }
        __syncthreads();
    }
    if (blockIdx.y == 0) {
#pragma unroll
        for (int nf = 0; nf < 8; ++nf)
#pragma unroll
            for (int j = 0; j < 4; ++j) {
                int row = r0 + w * 16 + g * 4 + j;
                if (row < N) Olh[(size_t)row * 128 + nf * 16 + m] = __float2half_rn(acc[nf][j]);
            }
    } else {
#pragma unroll
        for (int nf = 0; nf < 8; ++nf)
#pragma unroll
            for (int j = 0; j < 4; ++j) {
                int row = r0 + w * 16 + g * 4 + j;
                if (row < N) Or[(size_t)row * 128 + nf * 16 + m] = acc[nf][j];
            }
    }
}

// ---------------- Node kernel: fp16 xl gathers (256B/edge), bucket row coalesced + bpermute, ----------------
// ---------------- software-pipelined (ping-pong register sets) ----------------

#define UNPACK(R, XA, XB)                                                      \
    {                                                                          \
        __half2* hp_ = (__half2*)&(R);                                         \
        float2 f0_ = __half22float2(hp_[0]);                                   \
        float2 f1_ = __half22float2(hp_[1]);                                   \
        float2 f2_ = __half22float2(hp_[2]);                                   \
        float2 f3_ = __half22float2(hp_[3]);                                   \
        XA = make_float4(f0_.x, f0_.y, f1_.x, f1_.y);                          \
        XB = make_float4(f2_.x, f2_.y, f3_.x, f3_.y);                          \
    }

#define STAGE(IT, R0, R1, W0, W1, V0, V1)                                      \
    {                                                                          \
        int slot0 = (IT) * 8 + e4;                                             \
        int slot1 = slot0 + 4;                                                 \
        int s0i = __builtin_amdgcn_ds_bpermute(slot0 << 2, recAll.x);          \
        int w0i = __builtin_amdgcn_ds_bpermute(slot0 << 2, recAll.y);          \
        int s1i = __builtin_amdgcn_ds_bpermute(slot1 << 2, recAll.x);          \
        int w1i = __builtin_amdgcn_ds_bpermute(slot1 << 2, recAll.y);          \
        V0 = slot0 < deg; V1 = slot1 < deg;                                    \
        int off0 = ((V0 ? s0i : n) << 7) + d0;                                 \
        int off1 = ((V1 ? s1i : n) << 7) + d0;                                 \
        W0 = V0 ? __int_as_float(w0i) : 0.f;                                   \
        W1 = V1 ? __int_as_float(w1i) : 0.f;                                   \
        R0 = *(const int4*)(xl + off0);                                        \
        R1 = *(const int4*)(xl + off1);                                        \
    }

#define CONSUME(R0, R1, W0, W1, V0, V1)                                        \
    {                                                                          \
        float4 X0A, X0B, X1A, X1B;                                             \
        UNPACK(R0, X0A, X0B);                                                  \
        UNPACK(R1, X1A, X1B);                                                  \
        float t0 = fmaf(W0, weA.x, X0A.x + xrA.x);                             \
        float t1 = fmaf(W0, weA.y, X0A.y + xrA.y);                             \
        float t2 = fmaf(W0, weA.z, X0A.z + xrA.z);                             \
        float t3 = fmaf(W0, weA.w, X0A.w + xrA.w);                             \
        float t4 = fmaf(W0, weB.x, X0B.x + xrB.x);                             \
        float t5 = fmaf(W0, weB.y, X0B.y + xrB.y);                             \
        float t6 = fmaf(W0, weB.z, X0B.z + xrB.z);                             \
        float t7 = fmaf(W0, weB.w, X0B.w + xrB.w);                             \
        t0 = fmaxf(t0, NEG_SLOPE * t0); t1 = fmaxf(t1, NEG_SLOPE * t1);        \
        t2 = fmaxf(t2, NEG_SLOPE * t2); t3 = fmaxf(t3, NEG_SLOPE * t3);        \
        t4 = fmaxf(t4, NEG_SLOPE * t4); t5 = fmaxf(t5, NEG_SLOPE * t5);        \
        t6 = fmaxf(t6, NEG_SLOPE * t6); t7 = fmaxf(t7, NEG_SLOPE * t7);        \
        float p0 = t0 * atA.x + t1 * atA.y + t2 * atA.z + t3 * atA.w           \
                 + t4 * atB.x + t5 * atB.y + t6 * atB.z + t7 * atB.w;          \
        float u0 = fmaf(W1, weA.x, X1A.x + xrA.x);                             \
        float u1 = fmaf(W1, weA.y, X1A.y + xrA.y);                             \
        float u2 = fmaf(W1, weA.z, X1A.z + xrA.z);                             \
        float u3 = fmaf(W1, weA.w, X1A.w + xrA.w);                             \
        float u4 = fmaf(W1, weB.x, X1B.x + xrB.x);                             \
        float u5 = fmaf(W1, weB.y, X1B.y + xrB.y);                             \
        float u6 = fmaf(W1, weB.z, X1B.z + xrB.z);                             \
        float u7 = fmaf(W1, weB.w, X1B.w + xrB.w);                             \
        u0 = fmaxf(u0, NEG_SLOPE * u0); u1 = fmaxf(u1, NEG_SLOPE * u1);        \
        u2 = fmaxf(u2, NEG_SLOPE * u2); u3 = fmaxf(u3, NEG_SLOPE * u3);        \
        u4 = fmaxf(u4, NEG_SLOPE * u4); u5 = fmaxf(u5, NEG_SLOPE * u5);        \
        u6 = fmaxf(u6, NEG_SLOPE * u6); u7 = fmaxf(u7, NEG_SLOPE * u7);        \
        float p1 = u0 * atA.x + u1 * atA.y + u2 * atA.z + u3 * atA.w           \
                 + u4 * atB.x + u5 * atB.y + u6 * atB.z + u7 * atB.w;          \
        p0 += __shfl_xor(p0, 1); p1 += __shfl_xor(p1, 1);                      \
        p0 += __shfl_xor(p0, 2); p1 += __shfl_xor(p1, 2);                      \
        p0 += __shfl_xor(p0, 4); p1 += __shfl_xor(p1, 4);                      \
        float e0 = __expf(p0);                                                 \
        float e1 = __expf(p1);                                                 \
        e0 = V0 ? e0 : 0.f;                                                    \
        e1 = V1 ? e1 : 0.f;                                                    \
        den += e0 + e1;                                                        \
        wacc += W0 + W1;                                                       \
        a0 = fmaf(e0, X0A.x, fmaf(e1, X1A.x, a0));                             \
        a1 = fmaf(e0, X0A.y, fmaf(e1, X1A.y, a1));                             \
        a2 = fmaf(e0, X0A.z, fmaf(e1, X1A.z, a2));                             \
        a3 = fmaf(e0, X0A.w, fmaf(e1, X1A.w, a3));                             \
        a4 = fmaf(e0, X0B.x, fmaf(e1, X1B.x, a4));                             \
        a5 = fmaf(e0, X0B.y, fmaf(e1, X1B.y, a5));                             \
        a6 = fmaf(e0, X0B.z, fmaf(e1, X1B.z, a6));                             \
        a7 = fmaf(e0, X0B.w, fmaf(e1, X1B.w, a7));                             \
    }

__global__ __launch_bounds__(256) void k_node(const __half* __restrict__ xl, const float* __restrict__ xr,
                                              const int* __restrict__ cursor, const int2* __restrict__ bucket,
                                              const float* __restrict__ We, const float* __restrict__ att,
                                              const float* __restrict__ bias, float* __restrict__ out, int N) {
    int wid = threadIdx.x >> 6;
    int lane = threadIdx.x & 63;
    int n = blockIdx.x * 4 + wid;
    if (n >= N) return;
    int sub = lane & 15, e4 = lane >> 4;
    int d0 = sub * 8;
    float4 weA = *(const float4*)(We + d0),  weB = *(const float4*)(We + d0 + 4);
    float4 atA = *(const float4*)(att + d0), atB = *(const float4*)(att + d0 + 4);
    const float* xrp = xr + n * 128 + d0;
    float4 xrA = *(const float4*)xrp, xrB = *(const float4*)(xrp + 4);
    int beg = n * MAXDEG;
    int deg = cursor[n] - beg;
    int iters = (deg + 7) >> 3;
    int2 recAll = bucket[beg + lane];            // whole bucket row, one coalesced load
    float den = 0.f, wacc = 0.f;
    float a0 = 0.f, a1 = 0.f, a2 = 0.f, a3 = 0.f, a4 = 0.f, a5 = 0.f, a6 = 0.f, a7 = 0.f;

    int4 pR0, pR1; float pW0, pW1; bool pV0, pV1;
    int4 qR0, qR1; float qW0, qW1; bool qV0, qV1;
    STAGE(0, pR0, pR1, pW0, pW1, pV0, pV1);
    for (int it = 0; it < iters; ) {             // all branches wave-uniform (same n)
        if (it + 1 < iters) STAGE(it + 1, qR0, qR1, qW0, qW1, qV0, qV1);
        CONSUME(pR0, pR1, pW0, pW1, pV0, pV1);
        ++it;
        if (it >= iters) break;
        if (it + 1 < iters) STAGE(it + 1, pR0, pR1, pW0, pW1, pV0, pV1);
        CONSUME(qR0, qR1, qW0, qW1, qV0, qV1);
        ++it;
    }
#pragma unroll
    for (int off = 16; off <= 32; off <<= 1) {
        den += __shfl_xor(den, off);
        wacc += __shfl_xor(wacc, off);
        a0 += __shfl_xor(a0, off); a1 += __shfl_xor(a1, off);
        a2 += __shfl_xor(a2, off); a3 += __shfl_xor(a3, off);
        a4 += __shfl_xor(a4, off); a5 += __shfl_xor(a5, off);
        a6 += __shfl_xor(a6, off); a7 += __shfl_xor(a7, off);
    }
    // self-loop: weight = mean incoming edge weight, source feature = xl[n]
    {
        float lw = wacc / (float)max(deg, 1);
        int4 rawn = *(const int4*)(xl + (n << 7) + d0);
        float4 xA, xB;
        UNPACK(rawn, xA, xB);
        float t0 = fmaf(lw, weA.x, xA.x + xrA.x);
        float t1 = fmaf(lw, weA.y, xA.y + xrA.y);
        float t2 = fmaf(lw, weA.z, xA.z + xrA.z);
        float t3 = fmaf(lw, weA.w, xA.w + xrA.w);
        float t4 = fmaf(lw, weB.x, xB.x + xrB.x);
        float t5 = fmaf(lw, weB.y, xB.y + xrB.y);
        float t6 = fmaf(lw, weB.z, xB.z + xrB.z);
        float t7 = fmaf(lw, weB.w, xB.w + xrB.w);
        t0 = fmaxf(t0, NEG_SLOPE * t0); t1 = fmaxf(t1, NEG_SLOPE * t1);
        t2 = fmaxf(t2, NEG_SLOPE * t2); t3 = fmaxf(t3, NEG_SLOPE * t3);
        t4 = fmaxf(t4, NEG_SLOPE * t4); t5 = fmaxf(t5, NEG_SLOPE * t5);
        t6 = fmaxf(t6, NEG_SLOPE * t6); t7 = fmaxf(t7, NEG_SLOPE * t7);
        float p = t0 * atA.x + t1 * atA.y + t2 * atA.z + t3 * atA.w
                + t4 * atB.x + t5 * atB.y + t6 * atB.z + t7 * atB.w;
        p += __shfl_xor(p, 1);
        p += __shfl_xor(p, 2);
        p += __shfl_xor(p, 4);
        float e = __expf(p);
        den += e;
        a0 = fmaf(e, xA.x, a0); a1 = fmaf(e, xA.y, a1);
        a2 = fmaf(e, xA.z, a2); a3 = fmaf(e, xA.w, a3);
        a4 = fmaf(e, xB.x, a4); a5 = fmaf(e, xB.y, a5);
        a6 = fmaf(e, xB.z, a6); a7 = fmaf(e, xB.w, a7);
    }
    float inv = 1.f / den;
    float4 biA = *(const float4*)(bias + d0), biB = *(const float4*)(bias + d0 + 4);
    float o0 = a0 * inv + biA.x, o1 = a1 * inv + biA.y;
    float o2 = a2 * inv + biA.z, o3 = a3 * inv + biA.w;
    float o4 = a4 * inv + biB.x, o5 = a5 * inv + biB.y;
    float o6 = a6 * inv + biB.z, o7 = a7 * inv + biB.w;
    o0 = o0 > 0.f ? o0 : expm1f(o0); o1 = o1 > 0.f ? o1 : expm1f(o1);
    o2 = o2 > 0.f ? o2 : expm1f(o2); o3 = o3 > 0.f ? o3 : expm1f(o3);
    o4 = o4 > 0.f ? o4 : expm1f(o4); o5 = o5 > 0.f ? o5 : expm1f(o5);
    o6 = o6 > 0.f ? o6 : expm1f(o6); o7 = o7 > 0.f ? o7 : expm1f(o7);
    if (e4 == 0) {
        float* op = out + n * 128 + d0;
        *(float4*)op       = make_float4(o0, o1, o2, o3);
        *(float4*)(op + 4) = make_float4(o4, o5, o6, o7);
    }
}

// ---------------- launch ----------------

extern "C" void kernel_launch(void* const* d_in, const int* in_sizes, int n_in,
                              void* d_out, int out_size, void* d_ws, size_t ws_size,
                              hipStream_t stream) {
    const int*   ei   = (const int*)d_in[0];
    const float* ew   = (const float*)d_in[1];
    const float* emb  = (const float*)d_in[2];
    const float* Wl   = (const float*)d_in[3];
    const float* Wr   = (const float*)d_in[4];
    const float* We   = (const float*)d_in[5];
    const float* att  = (const float*)d_in[6];
    const float* bias = (const float*)d_in[7];
    int E = in_sizes[1];
    int N = in_sizes[2] / 128;

    char* p = (char*)d_ws;
    auto alloc = [&](size_t bytes) { char* r = p; p += (bytes + 255) & ~(size_t)255; return r; };
    __half* xl    = (__half*)alloc((size_t)N * 128 * 2);
    float*  xr    = (float*)alloc((size_t)N * 128 * 4);
    int2*   bucket= (int2*)alloc(((size_t)N * MAXDEG + 64) * 8);
    int*    cursor= (int*)alloc((size_t)N * 4);
    short*  wtbuf = (short*)alloc((size_t)4 * 40960 * 2);
    if ((size_t)(p - (char*)d_ws) > ws_size) return;

    int ib = (N + 255) / 256;
    int fb = (E / 8 + 255) / 256;
    k_init<<<ib, 256, 0, stream>>>(cursor, N);
    k_fillb<<<fb, 256, 0, stream>>>(ei, ew, cursor, bucket, E);
    k_cvtW<<<4, 256, 0, stream>>>(Wl, Wr, wtbuf);

    int gb = (N + 63) / 64;
    int nb = (N + 3) / 4;
    const float* h = emb;
    for (int l = 0; l < 2; ++l) {
        float* outl = (float*)d_out;   // layer0 result lives in d_out, re-read by layer1 gemm
        k_gemm_mfma<<<dim3(gb, 2), 256, 0, stream>>>(h, wtbuf + (size_t)l * 81920, xl, xr, N);
        k_node<<<nb, 256, 0, stream>>>(xl, xr, cursor, bucket,
                                       We + (size_t)l * 128, att + (size_t)l * 128,
                                       bias + (size_t)l * 128, outl, N);
        h = outl;
    }
}

// Round 14
// 225.710 us; speedup vs baseline: 1.4957x; 1.0244x over previous
//
#include <hip/hip_runtime.h>
#include <hip/hip_fp16.h>
#include <cstdint>

#define NEG_SLOPE 0.2f
#define MAXDEG 64

typedef __attribute__((ext_vector_type(8))) short bf16x8;
typedef __attribute__((ext_vector_type(4))) float f32x4;
typedef _Float16 h2_t __attribute__((ext_vector_type(2)));

__device__ inline short bf16_rne(float x) {
    uint32_t u = __float_as_uint(x);
    return (short)((u + 0x7FFF + ((u >> 16) & 1)) >> 16);
}
__device__ inline float bf16_to_f32(short s) {
    uint32_t u = ((uint32_t)(uint16_t)s) << 16;
    return __uint_as_float(u);
}
__device__ inline float fdot2(__half2 a, __half2 b, float c) {
    return __builtin_amdgcn_fdot2(*(h2_t*)&a, *(h2_t*)&b, c, false);
}
// ROCm 7.2 hip_fp16.h lacks __hmax2 -> packed max via v_pk_max_f16
__device__ inline __half2 hmax2(__half2 a, __half2 b) {
    uint32_t au = *(uint32_t*)&a, bu = *(uint32_t*)&b, du;
    asm("v_pk_max_f16 %0, %1, %2" : "=v"(du) : "v"(au), "v"(bu));
    return *(__half2*)&du;
}

// ---------------- bucketed CSR build: 1 atomic per edge, 8 edges/thread ----------------

__global__ __launch_bounds__(256) void k_init(int* __restrict__ cursor, int N) {
    int i = blockIdx.x * 256 + threadIdx.x;
    if (i < N) cursor[i] = i * MAXDEG;
}

__global__ __launch_bounds__(256) void k_fillb(const int* __restrict__ ei, const float* __restrict__ ew,
                                               int* __restrict__ cursor, int2* __restrict__ bucket, int E) {
    int i0 = (blockIdx.x * 256 + threadIdx.x) * 8;
    if (i0 >= E) return;
    if (i0 + 7 < E) {
        int4 sa = *(const int4*)&ei[i0];
        int4 sb = *(const int4*)&ei[i0 + 4];
        int4 da = *(const int4*)&ei[E + i0];
        int4 db = *(const int4*)&ei[E + i0 + 4];
        float4 wa = *(const float4*)&ew[i0];
        float4 wb = *(const float4*)&ew[i0 + 4];
        int p0 = atomicAdd(&cursor[da.x], 1);
        int p1 = atomicAdd(&cursor[da.y], 1);
        int p2 = atomicAdd(&cursor[da.z], 1);
        int p3 = atomicAdd(&cursor[da.w], 1);
        int p4 = atomicAdd(&cursor[db.x], 1);
        int p5 = atomicAdd(&cursor[db.y], 1);
        int p6 = atomicAdd(&cursor[db.z], 1);
        int p7 = atomicAdd(&cursor[db.w], 1);
        bucket[p0] = make_int2(sa.x, __float_as_int(wa.x));
        bucket[p1] = make_int2(sa.y, __float_as_int(wa.y));
        bucket[p2] = make_int2(sa.z, __float_as_int(wa.z));
        bucket[p3] = make_int2(sa.w, __float_as_int(wa.w));
        bucket[p4] = make_int2(sb.x, __float_as_int(wb.x));
        bucket[p5] = make_int2(sb.y, __float_as_int(wb.y));
        bucket[p6] = make_int2(sb.z, __float_as_int(wb.z));
        bucket[p7] = make_int2(sb.w, __float_as_int(wb.w));
    } else {
        for (int i = i0; i < E; ++i) {
            int pos = atomicAdd(&cursor[ei[E + i]], 1);
            bucket[pos] = make_int2(ei[i], __float_as_int(ew[i]));
        }
    }
}

// ---------------- W pre-transform: Wt[n][k] bf16 hi/lo, chunked+padded for LDS copy ----------------
__global__ __launch_bounds__(256) void k_cvtW(const float* __restrict__ Wl, const float* __restrict__ Wr,
                                              short* __restrict__ wt) {
    int b = blockIdx.x;             // 0..3 = (layer, mat)
    int l = b >> 1, mat = b & 1;
    const float* W = (mat ? Wr : Wl) + (size_t)l * 16384;
    short* dst = wt + (size_t)b * 40960;
    int t = threadIdx.x;
    int n = t >> 1, half = t & 1;   // n 0..127, half 0..1
    for (int chunk = 0; chunk < 4; ++chunk) {
        short hi16[16], lo16[16];
#pragma unroll
        for (int i = 0; i < 16; ++i) {
            int kk = half * 16 + i;
            float x = W[(size_t)(chunk * 32 + kk) * 128 + n];
            short h = bf16_rne(x);
            float r = x - bf16_to_f32(h);
            hi16[i] = h;
            lo16[i] = bf16_rne(r);
        }
        short* base = dst + chunk * 10240;
#pragma unroll
        for (int i = 0; i < 16; ++i) {
            base[n * 40 + half * 16 + i] = hi16[i];
            base[5120 + n * 40 + half * 16 + i] = lo16[i];
        }
    }
}

// ---------------- MFMA GEMM: O = H@W via split-bf16 (hi+lo), 64 rows/block ----------------
__global__ __launch_bounds__(256) void k_gemm_mfma(const float* __restrict__ H, const short* __restrict__ wt,
                                                   __half* __restrict__ Olh, float* __restrict__ Or, int N) {
    __shared__ __align__(16) short smem[2560 + 2560 + 10240];
    short* Ahi = smem;
    short* Alo = smem + 2560;
    short* Wst = smem + 5120;
    const short* wtm = wt + (size_t)blockIdx.y * 40960;
    int t = threadIdx.x;
    int w = t >> 6, lane = t & 63;
    int m = lane & 15, g = lane >> 4;
    int r0 = blockIdx.x * 64;
    f32x4 acc[8];
#pragma unroll
    for (int i = 0; i < 8; ++i) acc[i] = (f32x4){0.f, 0.f, 0.f, 0.f};

    int rr = t >> 2, q = t & 3;
    for (int chunk = 0; chunk < 4; ++chunk) {
        const short* wsrc = wtm + chunk * 10240;
#pragma unroll
        for (int i = 0; i < 5; ++i) {
            int u = t + i * 256;
            *(int4*)&Wst[u * 8] = *(const int4*)&wsrc[u * 8];
        }
        {
            int r = r0 + rr;
            float v[8];
            if (r < N) {
                float4 a = *(const float4*)&H[(size_t)r * 128 + chunk * 32 + q * 8];
                float4 b = *(const float4*)&H[(size_t)r * 128 + chunk * 32 + q * 8 + 4];
                v[0] = a.x; v[1] = a.y; v[2] = a.z; v[3] = a.w;
                v[4] = b.x; v[5] = b.y; v[6] = b.z; v[7] = b.w;
            } else {
#pragma unroll
                for (int i = 0; i < 8; ++i) v[i] = 0.f;
            }
            short hi8[8], lo8[8];
#pragma unroll
            for (int i = 0; i < 8; ++i) {
                short h = bf16_rne(v[i]);
                hi8[i] = h;
                lo8[i] = bf16_rne(v[i] - bf16_to_f32(h));
            }
            *(int4*)&Ahi[rr * 40 + q * 8] = *(int4*)hi8;
            *(int4*)&Alo[rr * 40 + q * 8] = *(int4*)lo8;
        }
        __syncthreads();
        bf16x8 ahi = *(bf16x8*)&Ahi[(w * 16 + m) * 40 + g * 8];
        bf16x8 alo = *(bf16x8*)&Alo[(w * 16 + m) * 40 + g * 8];
#pragma unroll
        for (int nf = 0; nf < 8; ++nf) {
            bf16x8 bhi = *(bf16x8*)&Wst[(nf * 16 + m) * 40 + g * 8];
            bf16x8 blo = *(bf16x8*)&Wst[5120 + (nf * 16 + m) * 40 + g * 8];
            acc[nf] = __builtin_amdgcn_mfma_f32_16x16x32_bf16(ahi, bhi, acc[nf], 0, 0, 0);
            acc[nf] = __builtin_amdgcn_mfma_f32_16x16x32_bf16(alo, bhi, acc[nf], 0, 0, 0);
            acc[nf] = __builtin_amdgcn_mfma_f32_16x16x32_bf16(ahi, blo, acc[nf], 0, 0, 0);
        }
        __syncthreads();
    }
    if (blockIdx.y == 0) {
#pragma unroll
        for (int nf = 0; nf < 8; ++nf)
#pragma unroll
            for (int j = 0; j < 4; ++j) {
                int row = r0 + w * 16 + g * 4 + j;
                if (row < N) Olh[(size_t)row * 128 + nf * 16 + m] = __float2half_rn(acc[nf][j]);
            }
    } else {
#pragma unroll
        for (int nf = 0; nf < 8; ++nf)
#pragma unroll
            for (int j = 0; j < 4; ++j) {
                int row = r0 + w * 16 + g * 4 + j;
                if (row < N) Or[(size_t)row * 128 + nf * 16 + m] = acc[nf][j];
            }
    }
}

// ---------------- Node kernel: packed-fp16 score path (hadd2/hfma2/pk_max + v_dot2_f32_f16), ----------------
// ---------------- fp16 gathers, bucket row coalesced + bpermute, software-pipelined ----------------

#define STAGE(IT, R0, R1, W0, W1, V0, V1)                                      \
    {                                                                          \
        int slot0 = (IT) * 8 + e4;                                             \
        int slot1 = slot0 + 4;                                                 \
        int s0i = __builtin_amdgcn_ds_bpermute(slot0 << 2, recAll.x);          \
        int w0i = __builtin_amdgcn_ds_bpermute(slot0 << 2, recAll.y);          \
        int s1i = __builtin_amdgcn_ds_bpermute(slot1 << 2, recAll.x);          \
        int w1i = __builtin_amdgcn_ds_bpermute(slot1 << 2, recAll.y);          \
        V0 = slot0 < deg; V1 = slot1 < deg;                                    \
        int off0 = ((V0 ? s0i : n) << 7) + d0;                                 \
        int off1 = ((V1 ? s1i : n) << 7) + d0;                                 \
        W0 = V0 ? __int_as_float(w0i) : 0.f;                                   \
        W1 = V1 ? __int_as_float(w1i) : 0.f;                                   \
        R0 = *(const int4*)(xl + off0);                                        \
        R1 = *(const int4*)(xl + off1);                                        \
    }

#define CONSUME(R0, R1, W0, W1, V0, V1)                                        \
    {                                                                          \
        __half2* x0h = (__half2*)&(R0);                                        \
        __half2* x1h = (__half2*)&(R1);                                        \
        __half2 w0h = __half2half2(__float2half_rn(W0));                       \
        __half2 w1h = __half2half2(__float2half_rn(W1));                       \
        float p0 = 0.f, p1 = 0.f;                                              \
        _Pragma("unroll")                                                      \
        for (int i = 0; i < 4; ++i) {                                          \
            __half2 t0 = __hfma2(w0h, weh[i], __hadd2(x0h[i], xrh[i]));        \
            __half2 t1 = __hfma2(w1h, weh[i], __hadd2(x1h[i], xrh[i]));        \
            t0 = hmax2(t0, __hmul2(t0, sl2));                                  \
            t1 = hmax2(t1, __hmul2(t1, sl2));                                  \
            p0 = fdot2(t0, ath[i], p0);                                        \
            p1 = fdot2(t1, ath[i], p1);                                        \
        }                                                                      \
        p0 += __shfl_xor(p0, 1); p1 += __shfl_xor(p1, 1);                      \
        p0 += __shfl_xor(p0, 2); p1 += __shfl_xor(p1, 2);                      \
        p0 += __shfl_xor(p0, 4); p1 += __shfl_xor(p1, 4);                      \
        float e0 = exp2f(p0);                                                  \
        float e1 = exp2f(p1);                                                  \
        e0 = V0 ? e0 : 0.f;                                                    \
        e1 = V1 ? e1 : 0.f;                                                    \
        den += e0 + e1;                                                        \
        wacc += W0 + W1;                                                       \
        _Pragma("unroll")                                                      \
        for (int i = 0; i < 4; ++i) {                                          \
            float2 f0 = __half22float2(x0h[i]);                                \
            float2 f1 = __half22float2(x1h[i]);                                \
            a[2*i]   = fmaf(e0, f0.x, fmaf(e1, f1.x, a[2*i]));                 \
            a[2*i+1] = fmaf(e0, f0.y, fmaf(e1, f1.y, a[2*i+1]));               \
        }                                                                      \
    }

__global__ __launch_bounds__(256) void k_node(const __half* __restrict__ xl, const float* __restrict__ xr,
                                              const int* __restrict__ cursor, const int2* __restrict__ bucket,
                                              const float* __restrict__ We, const float* __restrict__ att,
                                              const float* __restrict__ bias, float* __restrict__ out, int N) {
    int wid = threadIdx.x >> 6;
    int lane = threadIdx.x & 63;
    int n = blockIdx.x * 4 + wid;
    if (n >= N) return;
    int sub = lane & 15, e4 = lane >> 4;
    int d0 = sub * 8;
    const float LOG2E = 1.44269504f;
    __half2 weh[4], ath[4], xrh[4];
    {
        float4 weA = *(const float4*)(We + d0),  weB = *(const float4*)(We + d0 + 4);
        float4 atA = *(const float4*)(att + d0), atB = *(const float4*)(att + d0 + 4);
        const float* xrp = xr + n * 128 + d0;
        float4 xrA = *(const float4*)xrp, xrB = *(const float4*)(xrp + 4);
        weh[0] = __floats2half2_rn(weA.x, weA.y); weh[1] = __floats2half2_rn(weA.z, weA.w);
        weh[2] = __floats2half2_rn(weB.x, weB.y); weh[3] = __floats2half2_rn(weB.z, weB.w);
        ath[0] = __floats2half2_rn(atA.x * LOG2E, atA.y * LOG2E);
        ath[1] = __floats2half2_rn(atA.z * LOG2E, atA.w * LOG2E);
        ath[2] = __floats2half2_rn(atB.x * LOG2E, atB.y * LOG2E);
        ath[3] = __floats2half2_rn(atB.z * LOG2E, atB.w * LOG2E);
        xrh[0] = __floats2half2_rn(xrA.x, xrA.y); xrh[1] = __floats2half2_rn(xrA.z, xrA.w);
        xrh[2] = __floats2half2_rn(xrB.x, xrB.y); xrh[3] = __floats2half2_rn(xrB.z, xrB.w);
    }
    __half2 sl2 = __half2half2(__float2half_rn(NEG_SLOPE));
    int beg = n * MAXDEG;
    int deg = cursor[n] - beg;
    int iters = (deg + 7) >> 3;
    int2 recAll = bucket[beg + lane];            // whole bucket row, one coalesced load
    float den = 0.f, wacc = 0.f;
    float a[8] = {};

    int4 pR0, pR1; float pW0, pW1; bool pV0, pV1;
    int4 qR0, qR1; float qW0, qW1; bool qV0, qV1;
    STAGE(0, pR0, pR1, pW0, pW1, pV0, pV1);
    for (int it = 0; it < iters; ) {             // all branches wave-uniform (same n)
        if (it + 1 < iters) STAGE(it + 1, qR0, qR1, qW0, qW1, qV0, qV1);
        CONSUME(pR0, pR1, pW0, pW1, pV0, pV1);
        ++it;
        if (it >= iters) break;
        if (it + 1 < iters) STAGE(it + 1, pR0, pR1, pW0, pW1, pV0, pV1);
        CONSUME(qR0, qR1, qW0, qW1, qV0, qV1);
        ++it;
    }
#pragma unroll
    for (int off = 16; off <= 32; off <<= 1) {
        den += __shfl_xor(den, off);
        wacc += __shfl_xor(wacc, off);
#pragma unroll
        for (int i = 0; i < 8; ++i) a[i] += __shfl_xor(a[i], off);
    }
    // self-loop: weight = mean incoming edge weight, source feature = xl[n] (same packed path)
    {
        float lw = wacc / (float)max(deg, 1);
        int4 rawn = *(const int4*)(xl + (n << 7) + d0);
        __half2* xh = (__half2*)&rawn;
        __half2 lwh = __half2half2(__float2half_rn(lw));
        float p = 0.f;
#pragma unroll
        for (int i = 0; i < 4; ++i) {
            __half2 t = __hfma2(lwh, weh[i], __hadd2(xh[i], xrh[i]));
            t = hmax2(t, __hmul2(t, sl2));
            p = fdot2(t, ath[i], p);
        }
        p += __shfl_xor(p, 1);
        p += __shfl_xor(p, 2);
        p += __shfl_xor(p, 4);
        float e = exp2f(p);
        den += e;
#pragma unroll
        for (int i = 0; i < 4; ++i) {
            float2 f = __half22float2(xh[i]);
            a[2*i]   = fmaf(e, f.x, a[2*i]);
            a[2*i+1] = fmaf(e, f.y, a[2*i+1]);
        }
    }
    float inv = 1.f / den;
    float4 biA = *(const float4*)(bias + d0), biB = *(const float4*)(bias + d0 + 4);
    float o0 = a[0] * inv + biA.x, o1 = a[1] * inv + biA.y;
    float o2 = a[2] * inv + biA.z, o3 = a[3] * inv + biA.w;
    float o4 = a[4] * inv + biB.x, o5 = a[5] * inv + biB.y;
    float o6 = a[6] * inv + biB.z, o7 = a[7] * inv + biB.w;
    o0 = o0 > 0.f ? o0 : expm1f(o0); o1 = o1 > 0.f ? o1 : expm1f(o1);
    o2 = o2 > 0.f ? o2 : expm1f(o2); o3 = o3 > 0.f ? o3 : expm1f(o3);
    o4 = o4 > 0.f ? o4 : expm1f(o4); o5 = o5 > 0.f ? o5 : expm1f(o5);
    o6 = o6 > 0.f ? o6 : expm1f(o6); o7 = o7 > 0.f ? o7 : expm1f(o7);
    if (e4 == 0) {
        float* op = out + n * 128 + d0;
        *(float4*)op       = make_float4(o0, o1, o2, o3);
        *(float4*)(op + 4) = make_float4(o4, o5, o6, o7);
    }
}

// ---------------- launch ----------------

extern "C" void kernel_launch(void* const* d_in, const int* in_sizes, int n_in,
                              void* d_out, int out_size, void* d_ws, size_t ws_size,
                              hipStream_t stream) {
    const int*   ei   = (const int*)d_in[0];
    const float* ew   = (const float*)d_in[1];
    const float* emb  = (const float*)d_in[2];
    const float* Wl   = (const float*)d_in[3];
    const float* Wr   = (const float*)d_in[4];
    const float* We   = (const float*)d_in[5];
    const float* att  = (const float*)d_in[6];
    const float* bias = (const float*)d_in[7];
    int E = in_sizes[1];
    int N = in_sizes[2] / 128;

    char* p = (char*)d_ws;
    auto alloc = [&](size_t bytes) { char* r = p; p += (bytes + 255) & ~(size_t)255; return r; };
    __half* xl    = (__half*)alloc((size_t)N * 128 * 2);
    float*  xr    = (float*)alloc((size_t)N * 128 * 4);
    int2*   bucket= (int2*)alloc(((size_t)N * MAXDEG + 64) * 8);
    int*    cursor= (int*)alloc((size_t)N * 4);
    short*  wtbuf = (short*)alloc((size_t)4 * 40960 * 2);
    if ((size_t)(p - (char*)d_ws) > ws_size) return;

    int ib = (N + 255) / 256;
    int fb = (E / 8 + 255) / 256;
    k_init<<<ib, 256, 0, stream>>>(cursor, N);
    k_fillb<<<fb, 256, 0, stream>>>(ei, ew, cursor, bucket, E);
    k_cvtW<<<4, 256, 0, stream>>>(Wl, Wr, wtbuf);

    int gb = (N + 63) / 64;
    int nb = (N + 3) / 4;
    const float* h = emb;
    for (int l = 0; l < 2; ++l) {
        float* outl = (float*)d_out;   // layer0 result lives in d_out, re-read by layer1 gemm
        k_gemm_mfma<<<dim3(gb, 2), 256, 0, stream>>>(h, wtbuf + (size_t)l * 81920, xl, xr, N);
        k_node<<<nb, 256, 0, stream>>>(xl, xr, cursor, bucket,
                                       We + (size_t)l * 128, att + (size_t)l * 128,
                                       bias + (size_t)l * 128, outl, N);
        h = outl;
    }
}

// Round 16
// 212.484 us; speedup vs baseline: 1.5888x; 1.0622x over previous
//
#include <hip/hip_runtime.h>
#include <hip/hip_fp16.h>
#include <cstdint>

#define NEG_SLOPE 0.2f
#define MAXDEG 64

typedef __attribute__((ext_vector_type(8))) short bf16x8;
typedef __attribute__((ext_vector_type(4))) float f32x4;
typedef _Float16 h2_t __attribute__((ext_vector_type(2)));

__device__ inline short bf16_rne(float x) {
    uint32_t u = __float_as_uint(x);
    return (short)((u + 0x7FFF + ((u >> 16) & 1)) >> 16);
}
__device__ inline float bf16_to_f32(short s) {
    uint32_t u = ((uint32_t)(uint16_t)s) << 16;
    return __uint_as_float(u);
}
__device__ inline float fdot2(__half2 a, __half2 b, float c) {
    return __builtin_amdgcn_fdot2(*(h2_t*)&a, *(h2_t*)&b, c, false);
}
// ROCm 7.2 hip_fp16.h lacks __hmax2 -> packed max via v_pk_max_f16
__device__ inline __half2 hmax2(__half2 a, __half2 b) {
    uint32_t au = *(uint32_t*)&a, bu = *(uint32_t*)&b, du;
    asm("v_pk_max_f16 %0, %1, %2" : "=v"(du) : "v"(au), "v"(bu));
    return *(__half2*)&du;
}
// DPP all-reduce within 8-lane groups (VALU-speed, avoids LDS-pipe shfl latency).
// ctrl must be a compile-time constant -> template parameters.
template <int CTRL, int RMASK, int BMASK, bool BC>
__device__ inline float dpp_add(float v) {
    int t = __builtin_amdgcn_update_dpp(0, __float_as_int(v), CTRL, RMASK, BMASK, BC);
    return v + __int_as_float(t);
}
__device__ inline float red8(float p) {                        // sum over 8-lane head group
    p = dpp_add<0xB1, 0xF, 0xF, true>(p);   // quad_perm [1,0,3,2] : xor 1
    p = dpp_add<0x4E, 0xF, 0xF, true>(p);   // quad_perm [2,3,0,1] : xor 2
    int a = __builtin_amdgcn_update_dpp(0, __float_as_int(p), 0x114, 0xF, 0xA, false); // row_shr:4 -> banks 1,3
    int b = __builtin_amdgcn_update_dpp(0, __float_as_int(p), 0x104, 0xF, 0x5, false); // row_shl:4 -> banks 0,2
    return p + __int_as_float(a) + __int_as_float(b);
}

// ---------------- bucketed CSR build: 1 atomic per edge, 8 edges/thread ----------------

__global__ __launch_bounds__(256) void k_init(int* __restrict__ cursor, int N) {
    int i = blockIdx.x * 256 + threadIdx.x;
    if (i < N) cursor[i] = i * MAXDEG;
}

__global__ __launch_bounds__(256) void k_fillb(const int* __restrict__ ei, const float* __restrict__ ew,
                                               int* __restrict__ cursor, int2* __restrict__ bucket, int E) {
    int i0 = (blockIdx.x * 256 + threadIdx.x) * 8;
    if (i0 >= E) return;
    if (i0 + 7 < E) {
        int4 sa = *(const int4*)&ei[i0];
        int4 sb = *(const int4*)&ei[i0 + 4];
        int4 da = *(const int4*)&ei[E + i0];
        int4 db = *(const int4*)&ei[E + i0 + 4];
        float4 wa = *(const float4*)&ew[i0];
        float4 wb = *(const float4*)&ew[i0 + 4];
        int p0 = atomicAdd(&cursor[da.x], 1);
        int p1 = atomicAdd(&cursor[da.y], 1);
        int p2 = atomicAdd(&cursor[da.z], 1);
        int p3 = atomicAdd(&cursor[da.w], 1);
        int p4 = atomicAdd(&cursor[db.x], 1);
        int p5 = atomicAdd(&cursor[db.y], 1);
        int p6 = atomicAdd(&cursor[db.z], 1);
        int p7 = atomicAdd(&cursor[db.w], 1);
        bucket[p0] = make_int2(sa.x, __float_as_int(wa.x));
        bucket[p1] = make_int2(sa.y, __float_as_int(wa.y));
        bucket[p2] = make_int2(sa.z, __float_as_int(wa.z));
        bucket[p3] = make_int2(sa.w, __float_as_int(wa.w));
        bucket[p4] = make_int2(sb.x, __float_as_int(wb.x));
        bucket[p5] = make_int2(sb.y, __float_as_int(wb.y));
        bucket[p6] = make_int2(sb.z, __float_as_int(wb.z));
        bucket[p7] = make_int2(sb.w, __float_as_int(wb.w));
    } else {
        for (int i = i0; i < E; ++i) {
            int pos = atomicAdd(&cursor[ei[E + i]], 1);
            bucket[pos] = make_int2(ei[i], __float_as_int(ew[i]));
        }
    }
}

// ---------------- W pre-transform: Wt[n][k] bf16 hi/lo, chunked+padded for LDS copy ----------------
__global__ __launch_bounds__(256) void k_cvtW(const float* __restrict__ Wl, const float* __restrict__ Wr,
                                              short* __restrict__ wt) {
    int b = blockIdx.x;             // 0..3 = (layer, mat)
    int l = b >> 1, mat = b & 1;
    const float* W = (mat ? Wr : Wl) + (size_t)l * 16384;
    short* dst = wt + (size_t)b * 40960;
    int t = threadIdx.x;
    int n = t >> 1, half = t & 1;   // n 0..127, half 0..1
    for (int chunk = 0; chunk < 4; ++chunk) {
        short hi16[16], lo16[16];
#pragma unroll
        for (int i = 0; i < 16; ++i) {
            int kk = half * 16 + i;
            float x = W[(size_t)(chunk * 32 + kk) * 128 + n];
            short h = bf16_rne(x);
            float r = x - bf16_to_f32(h);
            hi16[i] = h;
            lo16[i] = bf16_rne(r);
        }
        short* base = dst + chunk * 10240;
#pragma unroll
        for (int i = 0; i < 16; ++i) {
            base[n * 40 + half * 16 + i] = hi16[i];
            base[5120 + n * 40 + half * 16 + i] = lo16[i];
        }
    }
}

// ---------------- MFMA GEMM: O = H@W via split-bf16 (hi+lo), 64 rows/block ----------------
__global__ __launch_bounds__(256) void k_gemm_mfma(const float* __restrict__ H, const short* __restrict__ wt,
                                                   __half* __restrict__ Olh, float* __restrict__ Or, int N) {
    __shared__ __align__(16) short smem[2560 + 2560 + 10240];
    short* Ahi = smem;
    short* Alo = smem + 2560;
    short* Wst = smem + 5120;
    const short* wtm = wt + (size_t)blockIdx.y * 40960;
    int t = threadIdx.x;
    int w = t >> 6, lane = t & 63;
    int m = lane & 15, g = lane >> 4;
    int r0 = blockIdx.x * 64;
    f32x4 acc[8];
#pragma unroll
    for (int i = 0; i < 8; ++i) acc[i] = (f32x4){0.f, 0.f, 0.f, 0.f};

    int rr = t >> 2, q = t & 3;
    for (int chunk = 0; chunk < 4; ++chunk) {
        const short* wsrc = wtm + chunk * 10240;
#pragma unroll
        for (int i = 0; i < 5; ++i) {
            int u = t + i * 256;
            *(int4*)&Wst[u * 8] = *(const int4*)&wsrc[u * 8];
        }
        {
            int r = r0 + rr;
            float v[8];
            if (r < N) {
                float4 a = *(const float4*)&H[(size_t)r * 128 + chunk * 32 + q * 8];
                float4 b = *(const float4*)&H[(size_t)r * 128 + chunk * 32 + q * 8 + 4];
                v[0] = a.x; v[1] = a.y; v[2] = a.z; v[3] = a.w;
                v[4] = b.x; v[5] = b.y; v[6] = b.z; v[7] = b.w;
            } else {
#pragma unroll
                for (int i = 0; i < 8; ++i) v[i] = 0.f;
            }
            short hi8[8], lo8[8];
#pragma unroll
            for (int i = 0; i < 8; ++i) {
                short h = bf16_rne(v[i]);
                hi8[i] = h;
                lo8[i] = bf16_rne(v[i] - bf16_to_f32(h));
            }
            *(int4*)&Ahi[rr * 40 + q * 8] = *(int4*)hi8;
            *(int4*)&Alo[rr * 40 + q * 8] = *(int4*)lo8;
        }
        __syncthreads();
        bf16x8 ahi = *(bf16x8*)&Ahi[(w * 16 + m) * 40 + g * 8];
        bf16x8 alo = *(bf16x8*)&Alo[(w * 16 + m) * 40 + g * 8];
#pragma unroll
        for (int nf = 0; nf < 8; ++nf) {
            bf16x8 bhi = *(bf16x8*)&Wst[(nf * 16 + m) * 40 + g * 8];
            bf16x8 blo = *(bf16x8*)&Wst[5120 + (nf * 16 + m) * 40 + g * 8];
            acc[nf] = __builtin_amdgcn_mfma_f32_16x16x32_bf16(ahi, bhi, acc[nf], 0, 0, 0);
            acc[nf] = __builtin_amdgcn_mfma_f32_16x16x32_bf16(alo, bhi, acc[nf], 0, 0, 0);
            acc[nf] = __builtin_amdgcn_mfma_f32_16x16x32_bf16(ahi, blo, acc[nf], 0, 0, 0);
        }
        __syncthreads();
    }
    if (blockIdx.y == 0) {
#pragma unroll
        for (int nf = 0; nf < 8; ++nf)
#pragma unroll
            for (int j = 0; j < 4; ++j) {
                int row = r0 + w * 16 + g * 4 + j;
                if (row < N) Olh[(size_t)row * 128 + nf * 16 + m] = __float2half_rn(acc[nf][j]);
            }
    } else {
#pragma unroll
        for (int nf = 0; nf < 8; ++nf)
#pragma unroll
            for (int j = 0; j < 4; ++j) {
                int row = r0 + w * 16 + g * 4 + j;
                if (row < N) Or[(size_t)row * 128 + nf * 16 + m] = acc[nf][j];
            }
    }
}

// ---------------- Node kernel: packed-fp16 score + DPP head-reduce, fp16 gathers, ----------------
// ---------------- bucket row coalesced + bpermute, software-pipelined ----------------

#define STAGE(IT, R0, R1, W0, W1, V0, V1)                                      \
    {                                                                          \
        int slot0 = (IT) * 8 + e4;                                             \
        int slot1 = slot0 + 4;                                                 \
        int s0i = __builtin_amdgcn_ds_bpermute(slot0 << 2, recAll.x);          \
        int w0i = __builtin_amdgcn_ds_bpermute(slot0 << 2, recAll.y);          \
        int s1i = __builtin_amdgcn_ds_bpermute(slot1 << 2, recAll.x);          \
        int w1i = __builtin_amdgcn_ds_bpermute(slot1 << 2, recAll.y);          \
        V0 = slot0 < deg; V1 = slot1 < deg;                                    \
        int off0 = ((V0 ? s0i : n) << 7) + d0;                                 \
        int off1 = ((V1 ? s1i : n) << 7) + d0;                                 \
        W0 = V0 ? __int_as_float(w0i) : 0.f;                                   \
        W1 = V1 ? __int_as_float(w1i) : 0.f;                                   \
        R0 = *(const int4*)(xl + off0);                                        \
        R1 = *(const int4*)(xl + off1);                                        \
    }

#define CONSUME(R0, R1, W0, W1, V0, V1)                                        \
    {                                                                          \
        __half2* x0h = (__half2*)&(R0);                                        \
        __half2* x1h = (__half2*)&(R1);                                        \
        __half2 w0h = __half2half2(__float2half_rn(W0));                       \
        __half2 w1h = __half2half2(__float2half_rn(W1));                       \
        float p0 = 0.f, p1 = 0.f;                                              \
        _Pragma("unroll")                                                      \
        for (int i = 0; i < 4; ++i) {                                          \
            __half2 t0 = __hfma2(w0h, weh[i], __hadd2(x0h[i], xrh[i]));        \
            __half2 t1 = __hfma2(w1h, weh[i], __hadd2(x1h[i], xrh[i]));        \
            t0 = hmax2(t0, __hmul2(t0, sl2));                                  \
            t1 = hmax2(t1, __hmul2(t1, sl2));                                  \
            p0 = fdot2(t0, ath[i], p0);                                        \
            p1 = fdot2(t1, ath[i], p1);                                        \
        }                                                                      \
        p0 = red8(p0);                                                         \
        p1 = red8(p1);                                                         \
        float e0 = exp2f(p0);                                                  \
        float e1 = exp2f(p1);                                                  \
        e0 = V0 ? e0 : 0.f;                                                    \
        e1 = V1 ? e1 : 0.f;                                                    \
        den += e0 + e1;                                                        \
        wacc += W0 + W1;                                                       \
        _Pragma("unroll")                                                      \
        for (int i = 0; i < 4; ++i) {                                          \
            float2 f0 = __half22float2(x0h[i]);                                \
            float2 f1 = __half22float2(x1h[i]);                                \
            a[2*i]   = fmaf(e0, f0.x, fmaf(e1, f1.x, a[2*i]));                 \
            a[2*i+1] = fmaf(e0, f0.y, fmaf(e1, f1.y, a[2*i+1]));               \
        }                                                                      \
    }

__global__ __launch_bounds__(256) void k_node(const __half* __restrict__ xl, const float* __restrict__ xr,
                                              const int* __restrict__ cursor, const int2* __restrict__ bucket,
                                              const float* __restrict__ We, const float* __restrict__ att,
                                              const float* __restrict__ bias, float* __restrict__ out, int N) {
    int wid = threadIdx.x >> 6;
    int lane = threadIdx.x & 63;
    int n = blockIdx.x * 4 + wid;
    if (n >= N) return;
    int sub = lane & 15, e4 = lane >> 4;
    int d0 = sub * 8;
    const float LOG2E = 1.44269504f;
    __half2 weh[4], ath[4], xrh[4];
    {
        float4 weA = *(const float4*)(We + d0),  weB = *(const float4*)(We + d0 + 4);
        float4 atA = *(const float4*)(att + d0), atB = *(const float4*)(att + d0 + 4);
        const float* xrp = xr + n * 128 + d0;
        float4 xrA = *(const float4*)xrp, xrB = *(const float4*)(xrp + 4);
        weh[0] = __floats2half2_rn(weA.x, weA.y); weh[1] = __floats2half2_rn(weA.z, weA.w);
        weh[2] = __floats2half2_rn(weB.x, weB.y); weh[3] = __floats2half2_rn(weB.z, weB.w);
        ath[0] = __floats2half2_rn(atA.x * LOG2E, atA.y * LOG2E);
        ath[1] = __floats2half2_rn(atA.z * LOG2E, atA.w * LOG2E);
        ath[2] = __floats2half2_rn(atB.x * LOG2E, atB.y * LOG2E);
        ath[3] = __floats2half2_rn(atB.z * LOG2E, atB.w * LOG2E);
        xrh[0] = __floats2half2_rn(xrA.x, xrA.y); xrh[1] = __floats2half2_rn(xrA.z, xrA.w);
        xrh[2] = __floats2half2_rn(xrB.x, xrB.y); xrh[3] = __floats2half2_rn(xrB.z, xrB.w);
    }
    __half2 sl2 = __half2half2(__float2half_rn(NEG_SLOPE));
    int beg = n * MAXDEG;
    int deg = cursor[n] - beg;
    int iters = (deg + 7) >> 3;
    int2 recAll = bucket[beg + lane];            // whole bucket row, one coalesced load
    float den = 0.f, wacc = 0.f;
    float a[8] = {};

    int4 pR0, pR1; float pW0, pW1; bool pV0, pV1;
    int4 qR0, qR1; float qW0, qW1; bool qV0, qV1;
    STAGE(0, pR0, pR1, pW0, pW1, pV0, pV1);
    for (int it = 0; it < iters; ) {             // all branches wave-uniform (same n)
        if (it + 1 < iters) STAGE(it + 1, qR0, qR1, qW0, qW1, qV0, qV1);
        CONSUME(pR0, pR1, pW0, pW1, pV0, pV1);
        ++it;
        if (it >= iters) break;
        if (it + 1 < iters) STAGE(it + 1, pR0, pR1, pW0, pW1, pV0, pV1);
        CONSUME(qR0, qR1, qW0, qW1, qV0, qV1);
        ++it;
    }
#pragma unroll
    for (int off = 16; off <= 32; off <<= 1) {
        den += __shfl_xor(den, off);
        wacc += __shfl_xor(wacc, off);
#pragma unroll
        for (int i = 0; i < 8; ++i) a[i] += __shfl_xor(a[i], off);
    }
    // self-loop: weight = mean incoming edge weight, source feature = xl[n] (same packed path)
    {
        float lw = wacc / (float)max(deg, 1);
        int4 rawn = *(const int4*)(xl + (n << 7) + d0);
        __half2* xh = (__half2*)&rawn;
        __half2 lwh = __half2half2(__float2half_rn(lw));
        float p = 0.f;
#pragma unroll
        for (int i = 0; i < 4; ++i) {
            __half2 t = __hfma2(lwh, weh[i], __hadd2(xh[i], xrh[i]));
            t = hmax2(t, __hmul2(t, sl2));
            p = fdot2(t, ath[i], p);
        }
        p = red8(p);
        float e = exp2f(p);
        den += e;
#pragma unroll
        for (int i = 0; i < 4; ++i) {
            float2 f = __half22float2(xh[i]);
            a[2*i]   = fmaf(e, f.x, a[2*i]);
            a[2*i+1] = fmaf(e, f.y, a[2*i+1]);
        }
    }
    float inv = 1.f / den;
    float4 biA = *(const float4*)(bias + d0), biB = *(const float4*)(bias + d0 + 4);
    float o[8];
    o[0] = a[0] * inv + biA.x; o[1] = a[1] * inv + biA.y;
    o[2] = a[2] * inv + biA.z; o[3] = a[3] * inv + biA.w;
    o[4] = a[4] * inv + biB.x; o[5] = a[5] * inv + biB.y;
    o[6] = a[6] * inv + biB.z; o[7] = a[7] * inv + biB.w;
#pragma unroll
    for (int i = 0; i < 8; ++i)                  // ELU via hardware exp2 (abs err ~1e-7)
        o[i] = o[i] > 0.f ? o[i] : exp2f(o[i] * LOG2E) - 1.f;
    if (e4 == 0) {
        float* op = out + n * 128 + d0;
        *(float4*)op       = make_float4(o[0], o[1], o[2], o[3]);
        *(float4*)(op + 4) = make_float4(o[4], o[5], o[6], o[7]);
    }
}

// ---------------- launch ----------------

extern "C" void kernel_launch(void* const* d_in, const int* in_sizes, int n_in,
                              void* d_out, int out_size, void* d_ws, size_t ws_size,
                              hipStream_t stream) {
    const int*   ei   = (const int*)d_in[0];
    const float* ew   = (const float*)d_in[1];
    const float* emb  = (const float*)d_in[2];
    const float* Wl   = (const float*)d_in[3];
    const float* Wr   = (const float*)d_in[4];
    const float* We   = (const float*)d_in[5];
    const float* att  = (const float*)d_in[6];
    const float* bias = (const float*)d_in[7];
    int E = in_sizes[1];
    int N = in_sizes[2] / 128;

    char* p = (char*)d_ws;
    auto alloc = [&](size_t bytes) { char* r = p; p += (bytes + 255) & ~(size_t)255; return r; };
    __half* xl    = (__half*)alloc((size_t)N * 128 * 2);
    float*  xr    = (float*)alloc((size_t)N * 128 * 4);
    int2*   bucket= (int2*)alloc(((size_t)N * MAXDEG + 64) * 8);
    int*    cursor= (int*)alloc((size_t)N * 4);
    short*  wtbuf = (short*)alloc((size_t)4 * 40960 * 2);
    if ((size_t)(p - (char*)d_ws) > ws_size) return;

    int ib = (N + 255) / 256;
    int fb = (E / 8 + 255) / 256;
    k_init<<<ib, 256, 0, stream>>>(cursor, N);
    k_fillb<<<fb, 256, 0, stream>>>(ei, ew, cursor, bucket, E);
    k_cvtW<<<4, 256, 0, stream>>>(Wl, Wr, wtbuf);

    int gb = (N + 63) / 64;
    int nb = (N + 3) / 4;
    const float* h = emb;
    for (int l = 0; l < 2; ++l) {
        float* outl = (float*)d_out;   // layer0 result lives in d_out, re-read by layer1 gemm
        k_gemm_mfma<<<dim3(gb, 2), 256, 0, stream>>>(h, wtbuf + (size_t)l * 81920, xl, xr, N);
        k_node<<<nb, 256, 0, stream>>>(xl, xr, cursor, bucket,
                                       We + (size_t)l * 128, att + (size_t)l * 128,
                                       bias + (size_t)l * 128, outl, N);
        h = outl;
    }
}

// Round 17
// 204.575 us; speedup vs baseline: 1.6503x; 1.0387x over previous
//
#include <hip/hip_runtime.h>
#include <hip/hip_fp16.h>
#include <cstdint>

#define NEG_SLOPE 0.2f
#define MAXDEG 64

typedef __attribute__((ext_vector_type(8))) short bf16x8;
typedef __attribute__((ext_vector_type(4))) float f32x4;
typedef _Float16 h2_t __attribute__((ext_vector_type(2)));

__device__ inline short bf16_rne(float x) {
    uint32_t u = __float_as_uint(x);
    return (short)((u + 0x7FFF + ((u >> 16) & 1)) >> 16);
}
__device__ inline float bf16_to_f32(short s) {
    uint32_t u = ((uint32_t)(uint16_t)s) << 16;
    return __uint_as_float(u);
}
__device__ inline float fdot2(__half2 a, __half2 b, float c) {
    return __builtin_amdgcn_fdot2(*(h2_t*)&a, *(h2_t*)&b, c, false);
}
// ROCm 7.2 hip_fp16.h lacks __hmax2 -> packed max via v_pk_max_f16
__device__ inline __half2 hmax2(__half2 a, __half2 b) {
    uint32_t au = *(uint32_t*)&a, bu = *(uint32_t*)&b, du;
    asm("v_pk_max_f16 %0, %1, %2" : "=v"(du) : "v"(au), "v"(bu));
    return *(__half2*)&du;
}
// mixed-precision FMA: f32 = f32 * f16(lo/hi of u32) + f32 — fuses cvt+fma
__device__ inline float fma_mix_lo(float e, uint32_t xh, float c) {
    float d;
    asm("v_fma_mix_f32 %0, %1, %2, %3 op_sel_hi:[0,1,0]" : "=v"(d) : "v"(e), "v"(xh), "v"(c));
    return d;
}
__device__ inline float fma_mix_hi(float e, uint32_t xh, float c) {
    float d;
    asm("v_fma_mix_f32 %0, %1, %2, %3 op_sel:[0,1,0] op_sel_hi:[0,1,0]" : "=v"(d) : "v"(e), "v"(xh), "v"(c));
    return d;
}
// DPP all-reduce within 8-lane groups (VALU-speed, avoids LDS-pipe shfl latency).
template <int CTRL, int RMASK, int BMASK, bool BC>
__device__ inline float dpp_add(float v) {
    int t = __builtin_amdgcn_update_dpp(0, __float_as_int(v), CTRL, RMASK, BMASK, BC);
    return v + __int_as_float(t);
}
__device__ inline float red8(float p) {                        // sum over 8-lane head group
    p = dpp_add<0xB1, 0xF, 0xF, true>(p);   // quad_perm [1,0,3,2] : xor 1
    p = dpp_add<0x4E, 0xF, 0xF, true>(p);   // quad_perm [2,3,0,1] : xor 2
    int a = __builtin_amdgcn_update_dpp(0, __float_as_int(p), 0x114, 0xF, 0xA, false); // row_shr:4
    int b = __builtin_amdgcn_update_dpp(0, __float_as_int(p), 0x104, 0xF, 0x5, false); // row_shl:4
    return p + __int_as_float(a) + __int_as_float(b);
}

// ---------------- bucketed CSR build: 1 atomic per edge, 8 edges/thread ----------------

__global__ __launch_bounds__(256) void k_init(int* __restrict__ cursor, int N) {
    int i = blockIdx.x * 256 + threadIdx.x;
    if (i < N) cursor[i] = i * MAXDEG;
}

__global__ __launch_bounds__(256) void k_fillb(const int* __restrict__ ei, const float* __restrict__ ew,
                                               int* __restrict__ cursor, int2* __restrict__ bucket, int E) {
    int i0 = (blockIdx.x * 256 + threadIdx.x) * 8;
    if (i0 >= E) return;
    if (i0 + 7 < E) {
        int4 sa = *(const int4*)&ei[i0];
        int4 sb = *(const int4*)&ei[i0 + 4];
        int4 da = *(const int4*)&ei[E + i0];
        int4 db = *(const int4*)&ei[E + i0 + 4];
        float4 wa = *(const float4*)&ew[i0];
        float4 wb = *(const float4*)&ew[i0 + 4];
        int p0 = atomicAdd(&cursor[da.x], 1);
        int p1 = atomicAdd(&cursor[da.y], 1);
        int p2 = atomicAdd(&cursor[da.z], 1);
        int p3 = atomicAdd(&cursor[da.w], 1);
        int p4 = atomicAdd(&cursor[db.x], 1);
        int p5 = atomicAdd(&cursor[db.y], 1);
        int p6 = atomicAdd(&cursor[db.z], 1);
        int p7 = atomicAdd(&cursor[db.w], 1);
        bucket[p0] = make_int2(sa.x, __float_as_int(wa.x));
        bucket[p1] = make_int2(sa.y, __float_as_int(wa.y));
        bucket[p2] = make_int2(sa.z, __float_as_int(wa.z));
        bucket[p3] = make_int2(sa.w, __float_as_int(wa.w));
        bucket[p4] = make_int2(sb.x, __float_as_int(wb.x));
        bucket[p5] = make_int2(sb.y, __float_as_int(wb.y));
        bucket[p6] = make_int2(sb.z, __float_as_int(wb.z));
        bucket[p7] = make_int2(sb.w, __float_as_int(wb.w));
    } else {
        for (int i = i0; i < E; ++i) {
            int pos = atomicAdd(&cursor[ei[E + i]], 1);
            bucket[pos] = make_int2(ei[i], __float_as_int(ew[i]));
        }
    }
}

// ---------------- W pre-transform: Wt[n][k] bf16 hi/lo, chunked+padded for LDS copy ----------------
__global__ __launch_bounds__(256) void k_cvtW(const float* __restrict__ Wl, const float* __restrict__ Wr,
                                              short* __restrict__ wt) {
    int b = blockIdx.x;             // 0..3 = (layer, mat)
    int l = b >> 1, mat = b & 1;
    const float* W = (mat ? Wr : Wl) + (size_t)l * 16384;
    short* dst = wt + (size_t)b * 40960;
    int t = threadIdx.x;
    int n = t >> 1, half = t & 1;   // n 0..127, half 0..1
    for (int chunk = 0; chunk < 4; ++chunk) {
        short hi16[16], lo16[16];
#pragma unroll
        for (int i = 0; i < 16; ++i) {
            int kk = half * 16 + i;
            float x = W[(size_t)(chunk * 32 + kk) * 128 + n];
            short h = bf16_rne(x);
            float r = x - bf16_to_f32(h);
            hi16[i] = h;
            lo16[i] = bf16_rne(r);
        }
        short* base = dst + chunk * 10240;
#pragma unroll
        for (int i = 0; i < 16; ++i) {
            base[n * 40 + half * 16 + i] = hi16[i];
            base[5120 + n * 40 + half * 16 + i] = lo16[i];
        }
    }
}

// ---------------- MFMA GEMM: O = H@W via split-bf16 (hi+lo), 64 rows/block ----------------
__global__ __launch_bounds__(256) void k_gemm_mfma(const float* __restrict__ H, const short* __restrict__ wt,
                                                   __half* __restrict__ Olh, float* __restrict__ Or, int N) {
    __shared__ __align__(16) short smem[2560 + 2560 + 10240];
    short* Ahi = smem;
    short* Alo = smem + 2560;
    short* Wst = smem + 5120;
    const short* wtm = wt + (size_t)blockIdx.y * 40960;
    int t = threadIdx.x;
    int w = t >> 6, lane = t & 63;
    int m = lane & 15, g = lane >> 4;
    int r0 = blockIdx.x * 64;
    f32x4 acc[8];
#pragma unroll
    for (int i = 0; i < 8; ++i) acc[i] = (f32x4){0.f, 0.f, 0.f, 0.f};

    int rr = t >> 2, q = t & 3;
    for (int chunk = 0; chunk < 4; ++chunk) {
        const short* wsrc = wtm + chunk * 10240;
#pragma unroll
        for (int i = 0; i < 5; ++i) {
            int u = t + i * 256;
            *(int4*)&Wst[u * 8] = *(const int4*)&wsrc[u * 8];
        }
        {
            int r = r0 + rr;
            float v[8];
            if (r < N) {
                float4 a = *(const float4*)&H[(size_t)r * 128 + chunk * 32 + q * 8];
                float4 b = *(const float4*)&H[(size_t)r * 128 + chunk * 32 + q * 8 + 4];
                v[0] = a.x; v[1] = a.y; v[2] = a.z; v[3] = a.w;
                v[4] = b.x; v[5] = b.y; v[6] = b.z; v[7] = b.w;
            } else {
#pragma unroll
                for (int i = 0; i < 8; ++i) v[i] = 0.f;
            }
            short hi8[8], lo8[8];
#pragma unroll
            for (int i = 0; i < 8; ++i) {
                short h = bf16_rne(v[i]);
                hi8[i] = h;
                lo8[i] = bf16_rne(v[i] - bf16_to_f32(h));
            }
            *(int4*)&Ahi[rr * 40 + q * 8] = *(int4*)hi8;
            *(int4*)&Alo[rr * 40 + q * 8] = *(int4*)lo8;
        }
        __syncthreads();
        bf16x8 ahi = *(bf16x8*)&Ahi[(w * 16 + m) * 40 + g * 8];
        bf16x8 alo = *(bf16x8*)&Alo[(w * 16 + m) * 40 + g * 8];
#pragma unroll
        for (int nf = 0; nf < 8; ++nf) {
            bf16x8 bhi = *(bf16x8*)&Wst[(nf * 16 + m) * 40 + g * 8];
            bf16x8 blo = *(bf16x8*)&Wst[5120 + (nf * 16 + m) * 40 + g * 8];
            acc[nf] = __builtin_amdgcn_mfma_f32_16x16x32_bf16(ahi, bhi, acc[nf], 0, 0, 0);
            acc[nf] = __builtin_amdgcn_mfma_f32_16x16x32_bf16(alo, bhi, acc[nf], 0, 0, 0);
            acc[nf] = __builtin_amdgcn_mfma_f32_16x16x32_bf16(ahi, blo, acc[nf], 0, 0, 0);
        }
        __syncthreads();
    }
    if (blockIdx.y == 0) {
#pragma unroll
        for (int nf = 0; nf < 8; ++nf)
#pragma unroll
            for (int j = 0; j < 4; ++j) {
                int row = r0 + w * 16 + g * 4 + j;
                if (row < N) Olh[(size_t)row * 128 + nf * 16 + m] = __float2half_rn(acc[nf][j]);
            }
    } else {
#pragma unroll
        for (int nf = 0; nf < 8; ++nf)
#pragma unroll
            for (int j = 0; j < 4; ++j) {
                int row = r0 + w * 16 + g * 4 + j;
                if (row < N) Or[(size_t)row * 128 + nf * 16 + m] = acc[nf][j];
            }
    }
}

// ---------------- Node kernel: packed-fp16 score + DPP head-reduce + fma_mix accumulate ----------------

#define STAGE(IT, R0, R1, W0, W1, V0, V1)                                      \
    {                                                                          \
        int slot0 = (IT) * 8 + e4;                                             \
        int slot1 = slot0 + 4;                                                 \
        int s0i = __builtin_amdgcn_ds_bpermute(slot0 << 2, recAll.x);          \
        int w0i = __builtin_amdgcn_ds_bpermute(slot0 << 2, recAll.y);          \
        int s1i = __builtin_amdgcn_ds_bpermute(slot1 << 2, recAll.x);          \
        int w1i = __builtin_amdgcn_ds_bpermute(slot1 << 2, recAll.y);          \
        V0 = slot0 < deg; V1 = slot1 < deg;                                    \
        int off0 = ((V0 ? s0i : n) << 7) + d0;                                 \
        int off1 = ((V1 ? s1i : n) << 7) + d0;                                 \
        W0 = V0 ? __int_as_float(w0i) : 0.f;                                   \
        W1 = V1 ? __int_as_float(w1i) : 0.f;                                   \
        R0 = *(const int4*)(xl + off0);                                        \
        R1 = *(const int4*)(xl + off1);                                        \
    }

#define CONSUME(R0, R1, W0, W1, V0, V1)                                        \
    {                                                                          \
        __half2* x0h = (__half2*)&(R0);                                        \
        __half2* x1h = (__half2*)&(R1);                                        \
        uint32_t* x0u = (uint32_t*)&(R0);                                      \
        uint32_t* x1u = (uint32_t*)&(R1);                                      \
        __half2 w0h = __half2half2(__float2half_rn(W0));                       \
        __half2 w1h = __half2half2(__float2half_rn(W1));                       \
        float p0 = 0.f, p1 = 0.f;                                              \
        _Pragma("unroll")                                                      \
        for (int i = 0; i < 4; ++i) {                                          \
            __half2 t0 = __hfma2(w0h, weh[i], __hadd2(x0h[i], xrh[i]));        \
            __half2 t1 = __hfma2(w1h, weh[i], __hadd2(x1h[i], xrh[i]));        \
            t0 = hmax2(t0, __hmul2(t0, sl2));                                  \
            t1 = hmax2(t1, __hmul2(t1, sl2));                                  \
            p0 = fdot2(t0, ath[i], p0);                                        \
            p1 = fdot2(t1, ath[i], p1);                                        \
        }                                                                      \
        p0 = red8(p0);                                                         \
        p1 = red8(p1);                                                         \
        float e0 = exp2f(p0);                                                  \
        float e1 = exp2f(p1);                                                  \
        e0 = V0 ? e0 : 0.f;                                                    \
        e1 = V1 ? e1 : 0.f;                                                    \
        den += e0 + e1;                                                        \
        wacc += W0 + W1;                                                       \
        _Pragma("unroll")                                                      \
        for (int i = 0; i < 4; ++i) {                                          \
            a[2*i]   = fma_mix_lo(e0, x0u[i], a[2*i]);                         \
            a[2*i+1] = fma_mix_hi(e0, x0u[i], a[2*i+1]);                       \
            a[2*i]   = fma_mix_lo(e1, x1u[i], a[2*i]);                         \
            a[2*i+1] = fma_mix_hi(e1, x1u[i], a[2*i+1]);                       \
        }                                                                      \
    }

__global__ __launch_bounds__(256) void k_node(const __half* __restrict__ xl, const float* __restrict__ xr,
                                              const int* __restrict__ cursor, const int2* __restrict__ bucket,
                                              const float* __restrict__ We, const float* __restrict__ att,
                                              const float* __restrict__ bias, float* __restrict__ out, int N) {
    int wid = threadIdx.x >> 6;
    int lane = threadIdx.x & 63;
    int n = blockIdx.x * 4 + wid;
    if (n >= N) return;
    int sub = lane & 15, e4 = lane >> 4;
    int d0 = sub * 8;
    const float LOG2E = 1.44269504f;
    __half2 weh[4], ath[4], xrh[4];
    {
        float4 weA = *(const float4*)(We + d0),  weB = *(const float4*)(We + d0 + 4);
        float4 atA = *(const float4*)(att + d0), atB = *(const float4*)(att + d0 + 4);
        const float* xrp = xr + n * 128 + d0;
        float4 xrA = *(const float4*)xrp, xrB = *(const float4*)(xrp + 4);
        weh[0] = __floats2half2_rn(weA.x, weA.y); weh[1] = __floats2half2_rn(weA.z, weA.w);
        weh[2] = __floats2half2_rn(weB.x, weB.y); weh[3] = __floats2half2_rn(weB.z, weB.w);
        ath[0] = __floats2half2_rn(atA.x * LOG2E, atA.y * LOG2E);
        ath[1] = __floats2half2_rn(atA.z * LOG2E, atA.w * LOG2E);
        ath[2] = __floats2half2_rn(atB.x * LOG2E, atB.y * LOG2E);
        ath[3] = __floats2half2_rn(atB.z * LOG2E, atB.w * LOG2E);
        xrh[0] = __floats2half2_rn(xrA.x, xrA.y); xrh[1] = __floats2half2_rn(xrA.z, xrA.w);
        xrh[2] = __floats2half2_rn(xrB.x, xrB.y); xrh[3] = __floats2half2_rn(xrB.z, xrB.w);
    }
    __half2 sl2 = __half2half2(__float2half_rn(NEG_SLOPE));
    int beg = n * MAXDEG;
    int deg = cursor[n] - beg;
    int iters = (deg + 7) >> 3;
    int2 recAll = bucket[beg + lane];            // whole bucket row, one coalesced load
    float den = 0.f, wacc = 0.f;
    float a[8] = {};

    int4 pR0, pR1; float pW0, pW1; bool pV0, pV1;
    int4 qR0, qR1; float qW0, qW1; bool qV0, qV1;
    STAGE(0, pR0, pR1, pW0, pW1, pV0, pV1);
    for (int it = 0; it < iters; ) {             // all branches wave-uniform (same n)
        if (it + 1 < iters) STAGE(it + 1, qR0, qR1, qW0, qW1, qV0, qV1);
        CONSUME(pR0, pR1, pW0, pW1, pV0, pV1);
        ++it;
        if (it >= iters) break;
        if (it + 1 < iters) STAGE(it + 1, pR0, pR1, pW0, pW1, pV0, pV1);
        CONSUME(qR0, qR1, qW0, qW1, qV0, qV1);
        ++it;
    }
#pragma unroll
    for (int off = 16; off <= 32; off <<= 1) {
        den += __shfl_xor(den, off);
        wacc += __shfl_xor(wacc, off);
#pragma unroll
        for (int i = 0; i < 8; ++i) a[i] += __shfl_xor(a[i], off);
    }
    // self-loop: weight = mean incoming edge weight, source feature = xl[n] (same packed path)
    {
        float lw = wacc / (float)max(deg, 1);
        int4 rawn = *(const int4*)(xl + (n << 7) + d0);
        __half2* xh = (__half2*)&rawn;
        uint32_t* xu = (uint32_t*)&rawn;
        __half2 lwh = __half2half2(__float2half_rn(lw));
        float p = 0.f;
#pragma unroll
        for (int i = 0; i < 4; ++i) {
            __half2 t = __hfma2(lwh, weh[i], __hadd2(xh[i], xrh[i]));
            t = hmax2(t, __hmul2(t, sl2));
            p = fdot2(t, ath[i], p);
        }
        p = red8(p);
        float e = exp2f(p);
        den += e;
#pragma unroll
        for (int i = 0; i < 4; ++i) {
            a[2*i]   = fma_mix_lo(e, xu[i], a[2*i]);
            a[2*i+1] = fma_mix_hi(e, xu[i], a[2*i+1]);
        }
    }
    float inv = 1.f / den;
    float4 biA = *(const float4*)(bias + d0), biB = *(const float4*)(bias + d0 + 4);
    float o[8];
    o[0] = a[0] * inv + biA.x; o[1] = a[1] * inv + biA.y;
    o[2] = a[2] * inv + biA.z; o[3] = a[3] * inv + biA.w;
    o[4] = a[4] * inv + biB.x; o[5] = a[5] * inv + biB.y;
    o[6] = a[6] * inv + biB.z; o[7] = a[7] * inv + biB.w;
#pragma unroll
    for (int i = 0; i < 8; ++i)                  // ELU via hardware exp2 (abs err ~1e-7)
        o[i] = o[i] > 0.f ? o[i] : exp2f(o[i] * LOG2E) - 1.f;
    if (e4 == 0) {
        float* op = out + n * 128 + d0;
        *(float4*)op       = make_float4(o[0], o[1], o[2], o[3]);
        *(float4*)(op + 4) = make_float4(o[4], o[5], o[6], o[7]);
    }
}

// ---------------- launch ----------------

extern "C" void kernel_launch(void* const* d_in, const int* in_sizes, int n_in,
                              void* d_out, int out_size, void* d_ws, size_t ws_size,
                              hipStream_t stream) {
    const int*   ei   = (const int*)d_in[0];
    const float* ew   = (const float*)d_in[1];
    const float* emb  = (const float*)d_in[2];
    const float* Wl   = (const float*)d_in[3];
    const float* Wr   = (const float*)d_in[4];
    const float* We   = (const float*)d_in[5];
    const float* att  = (const float*)d_in[6];
    const float* bias = (const float*)d_in[7];
    int E = in_sizes[1];
    int N = in_sizes[2] / 128;

    char* p = (char*)d_ws;
    auto alloc = [&](size_t bytes) { char* r = p; p += (bytes + 255) & ~(size_t)255; return r; };
    __half* xl    = (__half*)alloc((size_t)N * 128 * 2);
    float*  xr    = (float*)alloc((size_t)N * 128 * 4);
    int2*   bucket= (int2*)alloc(((size_t)N * MAXDEG + 64) * 8);
    int*    cursor= (int*)alloc((size_t)N * 4);
    short*  wtbuf = (short*)alloc((size_t)4 * 40960 * 2);
    if ((size_t)(p - (char*)d_ws) > ws_size) return;

    int ib = (N + 255) / 256;
    int fb = (E / 8 + 255) / 256;
    k_init<<<ib, 256, 0, stream>>>(cursor, N);
    k_fillb<<<fb, 256, 0, stream>>>(ei, ew, cursor, bucket, E);
    k_cvtW<<<4, 256, 0, stream>>>(Wl, Wr, wtbuf);

    int gb = (N + 63) / 64;
    int nb = (N + 3) / 4;
    const float* h = emb;
    for (int l = 0; l < 2; ++l) {
        float* outl = (float*)d_out;   // layer0 result lives in d_out, re-read by layer1 gemm
        k_gemm_mfma<<<dim3(gb, 2), 256, 0, stream>>>(h, wtbuf + (size_t)l * 81920, xl, xr, N);
        k_node<<<nb, 256, 0, stream>>>(xl, xr, cursor, bucket,
                                       We + (size_t)l * 128, att + (size_t)l * 128,
                                       bias + (size_t)l * 128, outl, N);
        h = outl;
    }
}